// Round 1
// baseline (5518.348 us; speedup 1.0000x reference)
//
#include <hip/hip_runtime.h>
#include <hip/hip_bf16.h>
#include <math.h>

#define D_MODEL 2048
#define N_LAYERS 2
#define ED 4096
#define D_STATE 16
#define D_CONV 4
#define DT_RANK 128
#define N_HEADS 4
#define HEAD_DIM 512
#define BATCH 4
#define SEQL 256

// ---------------------------------------------------------------- utilities
__device__ __forceinline__ float warp_reduce_sum(float v) {
#pragma unroll
    for (int off = 1; off < 64; off <<= 1) v += __shfl_xor(v, off);
    return v;
}
__device__ __forceinline__ float warp_reduce_max(float v) {
#pragma unroll
    for (int off = 1; off < 64; off <<= 1) v = fmaxf(v, __shfl_xor(v, off));
    return v;
}

// ---------------------------------------------------------------- copy
__global__ void copy_kernel(const float* __restrict__ src, float* __restrict__ dst, int n) {
    int i = blockIdx.x * blockDim.x + threadIdx.x;
    if (i < n) dst[i] = src[i];
}

// ---------------------------------------------------------------- rmsnorm
// one block per row of D_MODEL
__global__ void rmsnorm_kernel(const float* __restrict__ x, const float* __restrict__ w,
                               float* __restrict__ o) {
    int row = blockIdx.x;
    int tid = threadIdx.x;  // 256
    const float* xr = x + (long)row * D_MODEL;
    float ss = 0.f;
    for (int i = tid; i < D_MODEL; i += 256) { float v = xr[i]; ss += v * v; }
    ss = warp_reduce_sum(ss);
    __shared__ float r[4];
    int wave = tid >> 6;
    if ((tid & 63) == 0) r[wave] = ss;
    __syncthreads();
    float tot = r[0] + r[1] + r[2] + r[3];
    float sc = rsqrtf(tot / (float)D_MODEL + 1e-5f);
    float* orow = o + (long)row * D_MODEL;
    for (int i = tid; i < D_MODEL; i += 256) orow[i] = xr[i] * sc * w[i];
}

// ---------------------------------------------------------------- GEMM
// C[M,N] = A[M,K](lda) * B[N,K]^T   (+ bias[n]) (+ C if accumulate)
// block = 256 threads, 64x64 tile, 4x4 per thread
__global__ void gemm_kernel(const float* __restrict__ A, int lda,
                            const float* __restrict__ B,
                            float* __restrict__ C, int ldc,
                            int M, int N, int K,
                            const float* __restrict__ bias, int accumulate) {
    const int BM = 64, BN = 64, BK = 16;
    __shared__ float As[BK][BM + 4];
    __shared__ float Bs[BK][BN + 4];
    int tid = threadIdx.x;
    int tx = tid & 15, ty = tid >> 4;
    int m0 = blockIdx.y * BM, n0 = blockIdx.x * BN;
    float acc[4][4] = {{0.f}};
    for (int k0 = 0; k0 < K; k0 += BK) {
#pragma unroll
        for (int j = 0; j < 4; ++j) {
            int i = tid + j * 256;
            int r = i >> 4;
            int c = i & 15;
            int gm = m0 + r, gk = k0 + c;
            As[c][r] = (gm < M && gk < K) ? A[(long)gm * lda + gk] : 0.f;
            int gn = n0 + r;
            Bs[c][r] = (gn < N && gk < K) ? B[(long)gn * K + gk] : 0.f;
        }
        __syncthreads();
#pragma unroll
        for (int kk = 0; kk < BK; ++kk) {
            float4 a = *(const float4*)&As[kk][ty * 4];
            float4 b = *(const float4*)&Bs[kk][tx * 4];
            float av[4] = {a.x, a.y, a.z, a.w};
            float bv[4] = {b.x, b.y, b.z, b.w};
#pragma unroll
            for (int i = 0; i < 4; ++i)
#pragma unroll
                for (int j = 0; j < 4; ++j) acc[i][j] += av[i] * bv[j];
        }
        __syncthreads();
    }
#pragma unroll
    for (int i = 0; i < 4; ++i) {
        int gm = m0 + ty * 4 + i;
        if (gm >= M) continue;
#pragma unroll
        for (int j = 0; j < 4; ++j) {
            int gn = n0 + tx * 4 + j;
            if (gn >= N) continue;
            float v = acc[i][j];
            if (bias) v += bias[gn];
            long idx = (long)gm * ldc + gn;
            if (accumulate) v += C[idx];
            C[idx] = v;
        }
    }
}

// ---------------------------------------------------------------- depthwise causal conv + bias + silu
// xz layout (B*L, 2*ED); xin = first ED cols. out xc (B*L, ED)
__global__ void conv_silu_kernel(const float* __restrict__ xz, const float* __restrict__ cw,
                                 const float* __restrict__ cb, float* __restrict__ xc) {
    long idx = (long)blockIdx.x * blockDim.x + threadIdx.x;  // B*L*ED
    int e = idx & (ED - 1);
    long bl = idx >> 12;  // /ED
    int l = bl & (SEQL - 1);
    float acc = cb[e];
#pragma unroll
    for (int j = 0; j < D_CONV; ++j) {
        int ll = l - (D_CONV - 1) + j;
        if (ll >= 0) acc += cw[e * D_CONV + j] * xz[(bl + (ll - l)) * (2 * ED) + e];
    }
    float s = acc / (1.f + expf(-acc));
    xc[idx] = s;
}

// ---------------------------------------------------------------- softplus(delta + bias)
__global__ void softplus_kernel(float* __restrict__ delta, const float* __restrict__ dt_b) {
    long idx = (long)blockIdx.x * blockDim.x + threadIdx.x;
    int e = idx & (ED - 1);
    float v = delta[idx] + dt_b[e];
    delta[idx] = (v > 20.f) ? v : log1pf(expf(v));
}

// ---------------------------------------------------------------- selective scan (fused dA/dBx/y/gate)
// one thread per (b,e). y[b,l,e] = (sum_n h*Cm + xc*Dp) * silu(z)
__global__ void scan_kernel(const float* __restrict__ delta, const float* __restrict__ dbc,
                            const float* __restrict__ xc, const float* __restrict__ xz,
                            const float* __restrict__ A_log, const float* __restrict__ Dp,
                            float* __restrict__ y) {
    int t = blockIdx.x * blockDim.x + threadIdx.x;  // B*ED
    int e = t & (ED - 1);
    int b = t >> 12;
    float Ar[D_STATE], h[D_STATE];
#pragma unroll
    for (int n = 0; n < D_STATE; ++n) {
        Ar[n] = -expf(A_log[(long)e * D_STATE + n]);
        h[n] = 0.f;
    }
    float dpe = Dp[e];
    for (int l = 0; l < SEQL; ++l) {
        long bl = (long)b * SEQL + l;
        float d = delta[bl * ED + e];
        float x = xc[bl * ED + e];
        float z = xz[bl * (2 * ED) + ED + e];
        const float* bc = dbc + bl * (DT_RANK + 2 * D_STATE) + DT_RANK;
        float yacc = 0.f;
        float dx = d * x;
#pragma unroll
        for (int n = 0; n < D_STATE; ++n) {
            float dA = __expf(d * Ar[n]);
            h[n] = dA * h[n] + dx * bc[n];
            yacc += h[n] * bc[D_STATE + n];
        }
        float yv = yacc + x * dpe;
        float zs = z / (1.f + __expf(-z));
        y[bl * ED + e] = yv * zs;
    }
}

// ---------------------------------------------------------------- attention (one block per b,h,q)
__global__ void attn_kernel(const float* __restrict__ qkv, float* __restrict__ ao) {
    int blk = blockIdx.x;
    int qi = blk & (SEQL - 1);
    int h = (blk >> 8) & (N_HEADS - 1);
    int b = blk >> 10;
    int tid = threadIdx.x;  // 256
    __shared__ float qs[HEAD_DIM];
    __shared__ float ps[SEQL];
    __shared__ float wred[4];

    const float* qrow = qkv + ((long)(b * SEQL + qi)) * (3 * D_MODEL) + h * HEAD_DIM;
    qs[tid] = qrow[tid];
    qs[tid + 256] = qrow[tid + 256];
    __syncthreads();

    const float* krow = qkv + ((long)(b * SEQL + tid)) * (3 * D_MODEL) + D_MODEL + h * HEAD_DIM;
    float s = 0.f;
#pragma unroll 8
    for (int d = 0; d < HEAD_DIM; d += 4) {
        float4 kv = *(const float4*)(krow + d);
        s += qs[d] * kv.x + qs[d + 1] * kv.y + qs[d + 2] * kv.z + qs[d + 3] * kv.w;
    }
    s *= 0.044194173824159216f;  // 1/sqrt(512)

    float m = warp_reduce_max(s);
    int wave = tid >> 6;
    if ((tid & 63) == 0) wred[wave] = m;
    __syncthreads();
    float gm = fmaxf(fmaxf(wred[0], wred[1]), fmaxf(wred[2], wred[3]));
    __syncthreads();
    float p = __expf(s - gm);
    float sum = warp_reduce_sum(p);
    if ((tid & 63) == 0) wred[wave] = sum;
    __syncthreads();
    float gs = wred[0] + wred[1] + wred[2] + wred[3];
    ps[tid] = p / gs;
    __syncthreads();

    float acc0 = 0.f, acc1 = 0.f;
    const float* vbase = qkv + (long)b * SEQL * (3 * D_MODEL) + 2 * D_MODEL + h * HEAD_DIM;
    for (int t = 0; t < SEQL; ++t) {
        float pt = ps[t];
        const float* vrow = vbase + (long)t * (3 * D_MODEL);
        acc0 += pt * vrow[tid];
        acc1 += pt * vrow[tid + 256];
    }
    float* aorow = ao + ((long)(b * SEQL + qi)) * D_MODEL + h * HEAD_DIM;
    aorow[tid] = acc0;
    aorow[tid + 256] = acc1;
}

// ---------------------------------------------------------------- head (one block per batch, 1024 thr)
__global__ void head_kernel(const float* __restrict__ H, const float* __restrict__ w1,
                            const float* __restrict__ b1, const float* __restrict__ ln_g,
                            const float* __restrict__ ln_b, const float* __restrict__ w2,
                            const float* __restrict__ b2, float* __restrict__ out) {
    int b = blockIdx.x;
    int tid = threadIdx.x;  // 1024
    __shared__ float last[D_MODEL];
    __shared__ float hm[1024];
    __shared__ float r1[16], r2[16];
    __shared__ float stats[2];

    const float* hrow = H + ((long)(b * SEQL + SEQL - 1)) * D_MODEL;
    last[tid] = hrow[tid];
    last[tid + 1024] = hrow[tid + 1024];
    __syncthreads();

    float acc = b1[tid];
    const float* wr = w1 + (long)tid * D_MODEL;
#pragma unroll 4
    for (int d = 0; d < D_MODEL; d += 4) {
        float4 wv = *(const float4*)(wr + d);
        acc += last[d] * wv.x + last[d + 1] * wv.y + last[d + 2] * wv.z + last[d + 3] * wv.w;
    }
    float s1 = warp_reduce_sum(acc);
    float s2 = warp_reduce_sum(acc * acc);
    int wave = tid >> 6;
    if ((tid & 63) == 0) { r1[wave] = s1; r2[wave] = s2; }
    __syncthreads();
    if (tid == 0) {
        float t1 = 0.f, t2 = 0.f;
        for (int w = 0; w < 16; ++w) { t1 += r1[w]; t2 += r2[w]; }
        float mean = t1 / 1024.f;
        float var = t2 / 1024.f - mean * mean;
        stats[0] = mean;
        stats[1] = rsqrtf(var + 1e-5f);
    }
    __syncthreads();
    float x = (acc - stats[0]) * stats[1] * ln_g[tid] + ln_b[tid];
    x = (x > 0.f) ? x : (expf(x) - 1.f);
    hm[tid] = x;
    __syncthreads();

    if (tid < 64) {
        float a = b2[tid];
        const float* w2r = w2 + (long)tid * 1024;
        for (int j = 0; j < 1024; ++j) a += hm[j] * w2r[j];
        float ss = a * a;
#pragma unroll
        for (int off = 1; off < 64; off <<= 1) ss += __shfl_xor(ss, off);
        float n2 = sqrtf(ss);
        out[b * 64 + tid] = a / fmaxf(n2, 1e-12f);
    }
}

// ---------------------------------------------------------------- launch
extern "C" void kernel_launch(void* const* d_in, const int* in_sizes, int n_in,
                              void* d_out, int out_size, void* d_ws, size_t ws_size,
                              hipStream_t stream) {
    const float* x = (const float*)d_in[0];
    const float* norm_w = (const float*)d_in[1];
    const float* in_proj_w = (const float*)d_in[2];
    const float* conv_w = (const float*)d_in[3];
    const float* conv_b = (const float*)d_in[4];
    const float* x_proj_w = (const float*)d_in[5];
    const float* dt_proj_w = (const float*)d_in[6];
    const float* dt_proj_b = (const float*)d_in[7];
    const float* A_log = (const float*)d_in[8];
    const float* D_param = (const float*)d_in[9];
    const float* out_proj_w = (const float*)d_in[10];
    const float* attn_in_w = (const float*)d_in[11];
    const float* attn_in_b = (const float*)d_in[12];
    const float* attn_out_w = (const float*)d_in[13];
    const float* attn_out_b = (const float*)d_in[14];
    const float* w1 = (const float*)d_in[15];
    const float* b1 = (const float*)d_in[16];
    const float* ln_g = (const float*)d_in[17];
    const float* ln_b = (const float*)d_in[18];
    const float* w2 = (const float*)d_in[19];
    const float* b2 = (const float*)d_in[20];

    float* ws = (float*)d_ws;
    const long S_H = (long)BATCH * SEQL * D_MODEL;          // 2,097,152
    const long S_XZ = (long)BATCH * SEQL * 2 * ED;          // 8,388,608
    const long S_XC = (long)BATCH * SEQL * ED;              // 4,194,304
    const long S_DBC = (long)BATCH * SEQL * (DT_RANK + 2 * D_STATE);  // 163,840

    float* H = ws;
    float* XN = H + S_H;
    float* XZ = XN + S_H;
    float* XC = XZ + S_XZ;
    float* DBC = XC + S_XC;
    float* DELTA = DBC + S_DBC;
    float* Y = DELTA + S_XC;
    float* AO = XC;  // reuse (attention phase only)

    const int M = BATCH * SEQL;  // 1024

    copy_kernel<<<(S_H + 255) / 256, 256, 0, stream>>>(x, H, (int)S_H);

    for (int i = 0; i < N_LAYERS; ++i) {
        rmsnorm_kernel<<<M, 256, 0, stream>>>(H, norm_w + (long)i * D_MODEL, XN);
        // xz = xn @ in_proj_w^T  (M x 2ED, K=D)
        gemm_kernel<<<dim3((2 * ED) / 64, M / 64), 256, 0, stream>>>(
            XN, D_MODEL, in_proj_w + (long)i * 2 * ED * D_MODEL, XZ, 2 * ED, M, 2 * ED, D_MODEL,
            nullptr, 0);
        conv_silu_kernel<<<(S_XC + 255) / 256, 256, 0, stream>>>(
            XZ, conv_w + (long)i * ED * D_CONV, conv_b + (long)i * ED, XC);
        // dbc = xc @ x_proj_w^T  (M x 160, K=ED)
        gemm_kernel<<<dim3(3, M / 64), 256, 0, stream>>>(
            XC, ED, x_proj_w + (long)i * (DT_RANK + 2 * D_STATE) * ED, DBC,
            DT_RANK + 2 * D_STATE, M, DT_RANK + 2 * D_STATE, ED, nullptr, 0);
        // delta_lin = dt @ dt_proj_w^T (M x ED, K=DT_RANK); dt = dbc[:, :128] (lda=160)
        gemm_kernel<<<dim3(ED / 64, M / 64), 256, 0, stream>>>(
            DBC, DT_RANK + 2 * D_STATE, dt_proj_w + (long)i * ED * DT_RANK, DELTA, ED, M, ED,
            DT_RANK, nullptr, 0);
        softplus_kernel<<<(S_XC + 255) / 256, 256, 0, stream>>>(DELTA, dt_proj_b + (long)i * ED);
        scan_kernel<<<(BATCH * ED) / 256, 256, 0, stream>>>(
            DELTA, DBC, XC, XZ, A_log + (long)i * ED * D_STATE, D_param + (long)i * ED, Y);
        // H += y @ out_proj_w^T  (M x D, K=ED)
        gemm_kernel<<<dim3(D_MODEL / 64, M / 64), 256, 0, stream>>>(
            Y, ED, out_proj_w + (long)i * D_MODEL * ED, H, D_MODEL, M, D_MODEL, ED, nullptr, 1);
    }

    // qkv = H @ attn_in_w^T + b  (M x 3D, K=D)
    gemm_kernel<<<dim3((3 * D_MODEL) / 64, M / 64), 256, 0, stream>>>(
        H, D_MODEL, attn_in_w, XZ, 3 * D_MODEL, M, 3 * D_MODEL, D_MODEL, attn_in_b, 0);
    attn_kernel<<<BATCH * N_HEADS * SEQL, 256, 0, stream>>>(XZ, AO);
    // H += AO @ attn_out_w^T + b
    gemm_kernel<<<dim3(D_MODEL / 64, M / 64), 256, 0, stream>>>(
        AO, D_MODEL, attn_out_w, H, D_MODEL, M, D_MODEL, D_MODEL, attn_out_b, 1);

    head_kernel<<<BATCH, 1024, 0, stream>>>(H, w1, b1, ln_g, ln_b, w2, b2, (float*)d_out);
}

// Round 2
// 1951.028 us; speedup vs baseline: 2.8284x; 2.8284x over previous
//
#include <hip/hip_runtime.h>
#include <hip/hip_bf16.h>
#include <math.h>

#define D_MODEL 2048
#define N_LAYERS 2
#define ED 4096
#define D_STATE 16
#define D_CONV 4
#define DT_RANK 128
#define N_HEADS 4
#define HEAD_DIM 512
#define BATCH 4
#define SEQL 256

typedef __bf16 bf16_t;
typedef bf16_t bf16x8 __attribute__((ext_vector_type(8)));
typedef float f32x4 __attribute__((ext_vector_type(4)));

// ---------------------------------------------------------------- utilities
__device__ __forceinline__ float warp_reduce_sum(float v) {
#pragma unroll
    for (int off = 1; off < 64; off <<= 1) v += __shfl_xor(v, off);
    return v;
}
__device__ __forceinline__ float warp_reduce_max(float v) {
#pragma unroll
    for (int off = 1; off < 64; off <<= 1) v = fmaxf(v, __shfl_xor(v, off));
    return v;
}

__device__ __forceinline__ void gload_lds16(const bf16_t* g, bf16_t* l) {
    __builtin_amdgcn_global_load_lds(
        (const __attribute__((address_space(1))) unsigned int*)g,
        (__attribute__((address_space(3))) unsigned int*)l, 16, 0, 0);
}

// ---------------------------------------------------------------- copy
__global__ void copy_kernel(const float* __restrict__ src, float* __restrict__ dst, int n) {
    int i = blockIdx.x * blockDim.x + threadIdx.x;
    if (i < n) dst[i] = src[i];
}

// f32 -> bf16 convert
__global__ void f2b_kernel(const float* __restrict__ src, bf16_t* __restrict__ dst, int n) {
    int i = blockIdx.x * blockDim.x + threadIdx.x;
    if (i < n) dst[i] = (bf16_t)src[i];
}

// pack dt columns (dbc[:, :128]) into contiguous bf16 [1024][128]
__global__ void dt_pack_kernel(const float* __restrict__ dbc, bf16_t* __restrict__ dt) {
    int i = blockIdx.x * blockDim.x + threadIdx.x;  // < 1024*128
    int row = i >> 7, col = i & 127;
    dt[i] = (bf16_t)dbc[row * (DT_RANK + 2 * D_STATE) + col];
}

// sum split-K partials
__global__ void ksum_kernel(const float* __restrict__ part, float* __restrict__ out, int n,
                            int nz, long stride) {
    int i = blockIdx.x * blockDim.x + threadIdx.x;
    if (i >= n) return;
    float s = 0.f;
    for (int z = 0; z < nz; ++z) s += part[(long)z * stride + i];
    out[i] = s;
}

// ---------------------------------------------------------------- rmsnorm (bf16 out)
__global__ void rmsnorm_kernel(const float* __restrict__ x, const float* __restrict__ w,
                               bf16_t* __restrict__ o) {
    int row = blockIdx.x;
    int tid = threadIdx.x;  // 256
    const float* xr = x + (long)row * D_MODEL;
    float ss = 0.f;
    for (int i = tid; i < D_MODEL; i += 256) { float v = xr[i]; ss += v * v; }
    ss = warp_reduce_sum(ss);
    __shared__ float r[4];
    int wave = tid >> 6;
    if ((tid & 63) == 0) r[wave] = ss;
    __syncthreads();
    float tot = r[0] + r[1] + r[2] + r[3];
    float sc = rsqrtf(tot / (float)D_MODEL + 1e-5f);
    bf16_t* orow = o + (long)row * D_MODEL;
    for (int i = tid; i < D_MODEL; i += 256) orow[i] = (bf16_t)(xr[i] * sc * w[i]);
}

// ---------------------------------------------------------------- bf16 MFMA GEMM
// C[M=1024, N] = A[1024, K](bf16, lda) * B[N, K](fp32, ldb)^T
// 128x128 tile, 256 threads (4 waves, each 64x64 via 4x4 16x16x32 frags)
// A staged via global_load_lds (16B); B reg-staged fp32->bf16.
// gridDim.z > 1 => split-K partials at C + z*partial_stride (no bias/accum).
__global__ __launch_bounds__(256, 2) void gemm_bf16(
    const bf16_t* __restrict__ A, int lda, const float* __restrict__ B, int ldb,
    float* __restrict__ C, int ldc, int N, int K_len, const float* __restrict__ bias,
    int accumulate, int out_bf16, long partial_stride) {
    __shared__ bf16_t As[128 * 32];
    __shared__ bf16_t Bs[128 * 32];
    const int tid = threadIdx.x;
    const int lane = tid & 63;
    const int wave = tid >> 6;
    const int m0 = blockIdx.y * 128;
    const int n0 = blockIdx.x * 128;
    const int kbeg = blockIdx.z * K_len;

    // A staging: tile is [128][32] bf16 (8KB) = 8 chunks of 1KB; wave w stages chunks 2w,2w+1
    const int cA = wave * 2;
    const bf16_t* gA0 = A + (long)(m0 + cA * 16 + (lane >> 2)) * lda + kbeg + (lane & 3) * 8;
    const bf16_t* gA1 = gA0 + 16L * lda;
    bf16_t* lA0 = &As[cA * 512];
    bf16_t* lA1 = &As[cA * 512 + 512];

    // B staging: thread t handles row t>>1, 16-col half (t&1)
    const int brow = tid >> 1;
    const int bcol = (tid & 1) * 16;
    const bool bvalid = (n0 + brow) < N;
    const float* gB = B + (long)(n0 + brow) * ldb + kbeg + bcol;
    bf16_t* lB = &Bs[brow * 32 + bcol];

    const int wr = wave >> 1, wc = wave & 1;
    const int fr = lane & 15, fq = lane >> 4;
    const bf16_t* aBase = &As[(wr * 64 + fr) * 32 + fq * 8];
    const bf16_t* bBase = &Bs[(wc * 64 + fr) * 32 + fq * 8];

    f32x4 acc[4][4] = {};

    for (int kk = 0; kk < K_len; kk += 32) {
        gload_lds16(gA0, lA0);
        gload_lds16(gA1, lA1);
        gA0 += 32;
        gA1 += 32;
        if (bvalid) {
            float4 v0 = *(const float4*)(gB);
            float4 v1 = *(const float4*)(gB + 4);
            float4 v2 = *(const float4*)(gB + 8);
            float4 v3 = *(const float4*)(gB + 12);
            gB += 32;
            bf16x8 p0, p1;
            p0[0] = (bf16_t)v0.x; p0[1] = (bf16_t)v0.y; p0[2] = (bf16_t)v0.z; p0[3] = (bf16_t)v0.w;
            p0[4] = (bf16_t)v1.x; p0[5] = (bf16_t)v1.y; p0[6] = (bf16_t)v1.z; p0[7] = (bf16_t)v1.w;
            p1[0] = (bf16_t)v2.x; p1[1] = (bf16_t)v2.y; p1[2] = (bf16_t)v2.z; p1[3] = (bf16_t)v2.w;
            p1[4] = (bf16_t)v3.x; p1[5] = (bf16_t)v3.y; p1[6] = (bf16_t)v3.z; p1[7] = (bf16_t)v3.w;
            *(bf16x8*)lB = p0;
            *((bf16x8*)lB + 1) = p1;
        }
        __syncthreads();
        bf16x8 af[4], bfr[4];
#pragma unroll
        for (int m = 0; m < 4; ++m) af[m] = *(const bf16x8*)(aBase + m * 512);
#pragma unroll
        for (int n = 0; n < 4; ++n) bfr[n] = *(const bf16x8*)(bBase + n * 512);
#pragma unroll
        for (int m = 0; m < 4; ++m)
#pragma unroll
            for (int n = 0; n < 4; ++n)
                acc[m][n] = __builtin_amdgcn_mfma_f32_16x16x32_bf16(af[m], bfr[n], acc[m][n], 0, 0, 0);
        __syncthreads();
    }

    float* Cz = C + ((gridDim.z > 1) ? (long)blockIdx.z * partial_stride : 0L);
#pragma unroll
    for (int m = 0; m < 4; ++m) {
        const int grow0 = m0 + wr * 64 + m * 16 + fq * 4;
#pragma unroll
        for (int n = 0; n < 4; ++n) {
            const int gcol = n0 + wc * 64 + n * 16 + fr;
            if (gcol >= N) continue;
            float bv = bias ? bias[gcol] : 0.f;
#pragma unroll
            for (int r = 0; r < 4; ++r) {
                long idx = (long)(grow0 + r) * ldc + gcol;
                float v = acc[m][n][r] + bv;
                if (out_bf16) {
                    ((bf16_t*)Cz)[idx] = (bf16_t)v;
                } else {
                    if (accumulate) v += Cz[idx];
                    Cz[idx] = v;
                }
            }
        }
    }
}

// ---------------------------------------------------------------- depthwise causal conv + silu
// xzb (B*L, 2*ED) bf16; xin = first ED cols -> xcb (B*L, ED) bf16
__global__ void conv_silu_kernel(const bf16_t* __restrict__ xzb, const float* __restrict__ cw,
                                 const float* __restrict__ cb, bf16_t* __restrict__ xcb) {
    long idx = (long)blockIdx.x * blockDim.x + threadIdx.x;  // B*L*ED
    int e = idx & (ED - 1);
    long bl = idx >> 12;
    int l = bl & (SEQL - 1);
    float acc = cb[e];
#pragma unroll
    for (int j = 0; j < D_CONV; ++j) {
        int ll = l - (D_CONV - 1) + j;
        if (ll >= 0) acc += cw[e * D_CONV + j] * (float)xzb[(bl + (ll - l)) * (2 * ED) + e];
    }
    float s = acc / (1.f + __expf(-acc));
    xcb[idx] = (bf16_t)s;
}

// ---------------------------------------------------------------- softplus(delta + bias), fp32
__global__ void softplus_kernel(float* __restrict__ delta, const float* __restrict__ dt_b) {
    long idx = (long)blockIdx.x * blockDim.x + threadIdx.x;
    int e = idx & (ED - 1);
    float v = delta[idx] + dt_b[e];
    delta[idx] = (v > 20.f) ? v : log1pf(__expf(v));
}

// ---------------------------------------------------------------- selective scan
// one thread per (b,e); 64-thread blocks to spread over CUs
__global__ void scan_kernel(const float* __restrict__ delta, const float* __restrict__ dbc,
                            const bf16_t* __restrict__ xcb, const bf16_t* __restrict__ xzb,
                            const float* __restrict__ A_log, const float* __restrict__ Dp,
                            bf16_t* __restrict__ y) {
    int t = blockIdx.x * blockDim.x + threadIdx.x;  // B*ED
    int e = t & (ED - 1);
    int b = t >> 12;
    float Ar[D_STATE], h[D_STATE];
#pragma unroll
    for (int n = 0; n < D_STATE; ++n) {
        Ar[n] = -__expf(A_log[(long)e * D_STATE + n]);
        h[n] = 0.f;
    }
    float dpe = Dp[e];
    for (int l = 0; l < SEQL; ++l) {
        long bl = (long)b * SEQL + l;
        float d = delta[bl * ED + e];
        float x = (float)xcb[bl * ED + e];
        float z = (float)xzb[bl * (2 * ED) + ED + e];
        const float* bc = dbc + bl * (DT_RANK + 2 * D_STATE) + DT_RANK;
        float yacc = 0.f;
        float dx = d * x;
#pragma unroll
        for (int n = 0; n < D_STATE; ++n) {
            float dA = __expf(d * Ar[n]);
            h[n] = dA * h[n] + dx * bc[n];
            yacc += h[n] * bc[D_STATE + n];
        }
        float yv = yacc + x * dpe;
        float zs = z / (1.f + __expf(-z));
        y[bl * ED + e] = (bf16_t)(yv * zs);
    }
}

// ---------------------------------------------------------------- attention (one block per b,h,q)
__global__ void attn_kernel(const float* __restrict__ qkv, bf16_t* __restrict__ ao) {
    int blk = blockIdx.x;
    int qi = blk & (SEQL - 1);
    int h = (blk >> 8) & (N_HEADS - 1);
    int b = blk >> 10;
    int tid = threadIdx.x;  // 256
    __shared__ float qs[HEAD_DIM];
    __shared__ float ps[SEQL];
    __shared__ float wred[4];

    const float* qrow = qkv + ((long)(b * SEQL + qi)) * (3 * D_MODEL) + h * HEAD_DIM;
    qs[tid] = qrow[tid];
    qs[tid + 256] = qrow[tid + 256];
    __syncthreads();

    const float* krow = qkv + ((long)(b * SEQL + tid)) * (3 * D_MODEL) + D_MODEL + h * HEAD_DIM;
    float s = 0.f;
#pragma unroll 8
    for (int d = 0; d < HEAD_DIM; d += 4) {
        float4 kv = *(const float4*)(krow + d);
        s += qs[d] * kv.x + qs[d + 1] * kv.y + qs[d + 2] * kv.z + qs[d + 3] * kv.w;
    }
    s *= 0.044194173824159216f;  // 1/sqrt(512)

    float m = warp_reduce_max(s);
    int wave = tid >> 6;
    if ((tid & 63) == 0) wred[wave] = m;
    __syncthreads();
    float gm = fmaxf(fmaxf(wred[0], wred[1]), fmaxf(wred[2], wred[3]));
    __syncthreads();
    float p = __expf(s - gm);
    float sum = warp_reduce_sum(p);
    if ((tid & 63) == 0) wred[wave] = sum;
    __syncthreads();
    float gs = wred[0] + wred[1] + wred[2] + wred[3];
    ps[tid] = p / gs;
    __syncthreads();

    float acc0 = 0.f, acc1 = 0.f;
    const float* vbase = qkv + (long)b * SEQL * (3 * D_MODEL) + 2 * D_MODEL + h * HEAD_DIM;
    for (int t = 0; t < SEQL; ++t) {
        float pt = ps[t];
        const float* vrow = vbase + (long)t * (3 * D_MODEL);
        acc0 += pt * vrow[tid];
        acc1 += pt * vrow[tid + 256];
    }
    bf16_t* aorow = ao + ((long)(b * SEQL + qi)) * D_MODEL + h * HEAD_DIM;
    aorow[tid] = (bf16_t)acc0;
    aorow[tid + 256] = (bf16_t)acc1;
}

// ---------------------------------------------------------------- head (one block per batch)
__global__ void head_kernel(const float* __restrict__ H, const float* __restrict__ w1,
                            const float* __restrict__ b1, const float* __restrict__ ln_g,
                            const float* __restrict__ ln_b, const float* __restrict__ w2,
                            const float* __restrict__ b2, float* __restrict__ out) {
    int b = blockIdx.x;
    int tid = threadIdx.x;  // 1024
    __shared__ float last[D_MODEL];
    __shared__ float hm[1024];
    __shared__ float r1[16], r2[16];
    __shared__ float stats[2];

    const float* hrow = H + ((long)(b * SEQL + SEQL - 1)) * D_MODEL;
    last[tid] = hrow[tid];
    last[tid + 1024] = hrow[tid + 1024];
    __syncthreads();

    float acc = b1[tid];
    const float* wr = w1 + (long)tid * D_MODEL;
#pragma unroll 4
    for (int d = 0; d < D_MODEL; d += 4) {
        float4 wv = *(const float4*)(wr + d);
        acc += last[d] * wv.x + last[d + 1] * wv.y + last[d + 2] * wv.z + last[d + 3] * wv.w;
    }
    float s1 = warp_reduce_sum(acc);
    float s2 = warp_reduce_sum(acc * acc);
    int wave = tid >> 6;
    if ((tid & 63) == 0) { r1[wave] = s1; r2[wave] = s2; }
    __syncthreads();
    if (tid == 0) {
        float t1 = 0.f, t2 = 0.f;
        for (int w = 0; w < 16; ++w) { t1 += r1[w]; t2 += r2[w]; }
        float mean = t1 / 1024.f;
        float var = t2 / 1024.f - mean * mean;
        stats[0] = mean;
        stats[1] = rsqrtf(var + 1e-5f);
    }
    __syncthreads();
    float x = (acc - stats[0]) * stats[1] * ln_g[tid] + ln_b[tid];
    x = (x > 0.f) ? x : (__expf(x) - 1.f);
    hm[tid] = x;
    __syncthreads();

    if (tid < 64) {
        float a = b2[tid];
        const float* w2r = w2 + (long)tid * 1024;
        for (int j = 0; j < 1024; ++j) a += hm[j] * w2r[j];
        float ss = a * a;
#pragma unroll
        for (int off = 1; off < 64; off <<= 1) ss += __shfl_xor(ss, off);
        float n2 = sqrtf(ss);
        out[b * 64 + tid] = a / fmaxf(n2, 1e-12f);
    }
}

// ---------------------------------------------------------------- launch
extern "C" void kernel_launch(void* const* d_in, const int* in_sizes, int n_in,
                              void* d_out, int out_size, void* d_ws, size_t ws_size,
                              hipStream_t stream) {
    const float* x = (const float*)d_in[0];
    const float* norm_w = (const float*)d_in[1];
    const float* in_proj_w = (const float*)d_in[2];
    const float* conv_w = (const float*)d_in[3];
    const float* conv_b = (const float*)d_in[4];
    const float* x_proj_w = (const float*)d_in[5];
    const float* dt_proj_w = (const float*)d_in[6];
    const float* dt_proj_b = (const float*)d_in[7];
    const float* A_log = (const float*)d_in[8];
    const float* D_param = (const float*)d_in[9];
    const float* out_proj_w = (const float*)d_in[10];
    const float* attn_in_w = (const float*)d_in[11];
    const float* attn_in_b = (const float*)d_in[12];
    const float* attn_out_w = (const float*)d_in[13];
    const float* attn_out_b = (const float*)d_in[14];
    const float* w1 = (const float*)d_in[15];
    const float* b1 = (const float*)d_in[16];
    const float* ln_g = (const float*)d_in[17];
    const float* ln_b = (const float*)d_in[18];
    const float* w2 = (const float*)d_in[19];
    const float* b2 = (const float*)d_in[20];

    float* ws = (float*)d_ws;
    size_t o = 0;
    float* H = ws + o;      o += 2097152;       // (B,L,D) fp32
    float* SCR = ws + o;    o += 6291456;       // XZb (bf16, 8M elems) then QKV (fp32, 6M)
    float* DELTA = ws + o;  o += 4194304;       // (B,L,ED) fp32
    float* DBC = ws + o;    o += 163840;        // (B,L,160) fp32
    float* XPART = ws + o;  o += 1310720;       // 8 x (1024,160) split-K partials
    bf16_t* XNb = (bf16_t*)(ws + o);  o += 1048576;  // (B,L,D) bf16
    bf16_t* XCb = (bf16_t*)(ws + o);  o += 2097152;  // (B,L,ED) bf16
    bf16_t* DTb = (bf16_t*)(ws + o);  o += 65536;    // (1024,128) bf16
    bf16_t* Yb = (bf16_t*)(ws + o);   o += 2097152;  // (B,L,ED) bf16
    bf16_t* Hb = (bf16_t*)(ws + o);   o += 1048576;  // (B,L,D) bf16
    bf16_t* AOb = (bf16_t*)(ws + o);  o += 1048576;  // (B,L,D) bf16

    bf16_t* XZb = (bf16_t*)SCR;
    float* QKV = SCR;

    const int M = BATCH * SEQL;  // 1024
    const long S_H = (long)M * D_MODEL;
    const long S_XC = (long)M * ED;

    copy_kernel<<<(S_H + 255) / 256, 256, 0, stream>>>(x, H, (int)S_H);

    for (int i = 0; i < N_LAYERS; ++i) {
        rmsnorm_kernel<<<M, 256, 0, stream>>>(H, norm_w + (long)i * D_MODEL, XNb);
        // xz = xn @ in_proj_w^T  -> bf16 out
        gemm_bf16<<<dim3(64, 8, 1), 256, 0, stream>>>(
            XNb, D_MODEL, in_proj_w + (long)i * 2 * ED * D_MODEL, D_MODEL, (float*)XZb, 2 * ED,
            2 * ED, D_MODEL, nullptr, 0, 1, 0);
        conv_silu_kernel<<<(S_XC + 255) / 256, 256, 0, stream>>>(
            XZb, conv_w + (long)i * ED * D_CONV, conv_b + (long)i * ED, XCb);
        // dbc = xc @ x_proj_w^T  (split-K = 8)
        gemm_bf16<<<dim3(2, 8, 8), 256, 0, stream>>>(
            XCb, ED, x_proj_w + (long)i * (DT_RANK + 2 * D_STATE) * ED, ED, XPART,
            DT_RANK + 2 * D_STATE, DT_RANK + 2 * D_STATE, ED / 8, nullptr, 0, 0,
            (long)M * (DT_RANK + 2 * D_STATE));
        ksum_kernel<<<640, 256, 0, stream>>>(XPART, DBC, M * (DT_RANK + 2 * D_STATE), 8,
                                             (long)M * (DT_RANK + 2 * D_STATE));
        dt_pack_kernel<<<512, 256, 0, stream>>>(DBC, DTb);
        // delta_lin = dt @ dt_proj_w^T
        gemm_bf16<<<dim3(32, 8, 1), 256, 0, stream>>>(
            DTb, DT_RANK, dt_proj_w + (long)i * ED * DT_RANK, DT_RANK, DELTA, ED, ED, DT_RANK,
            nullptr, 0, 0, 0);
        softplus_kernel<<<(S_XC + 255) / 256, 256, 0, stream>>>(DELTA, dt_proj_b + (long)i * ED);
        scan_kernel<<<(BATCH * ED) / 64, 64, 0, stream>>>(
            DELTA, DBC, XCb, XZb, A_log + (long)i * ED * D_STATE, D_param + (long)i * ED, Yb);
        // H += y @ out_proj_w^T
        gemm_bf16<<<dim3(16, 8, 1), 256, 0, stream>>>(
            Yb, ED, out_proj_w + (long)i * D_MODEL * ED, ED, H, D_MODEL, D_MODEL, ED, nullptr, 1,
            0, 0);
    }

    f2b_kernel<<<(int)((S_H + 255) / 256), 256, 0, stream>>>(H, Hb, (int)S_H);
    // qkv = H @ attn_in_w^T + b
    gemm_bf16<<<dim3(48, 8, 1), 256, 0, stream>>>(Hb, D_MODEL, attn_in_w, D_MODEL, QKV,
                                                  3 * D_MODEL, 3 * D_MODEL, D_MODEL, attn_in_b, 0,
                                                  0, 0);
    attn_kernel<<<BATCH * N_HEADS * SEQL, 256, 0, stream>>>(QKV, AOb);
    // H += AO @ attn_out_w^T + b
    gemm_bf16<<<dim3(16, 8, 1), 256, 0, stream>>>(AOb, D_MODEL, attn_out_w, D_MODEL, H, D_MODEL,
                                                  D_MODEL, D_MODEL, attn_out_b, 1, 0, 0);

    head_kernel<<<BATCH, 1024, 0, stream>>>(H, w1, b1, ln_g, ln_b, w2, b2, (float*)d_out);
}

// Round 3
// 1402.860 us; speedup vs baseline: 3.9336x; 1.3908x over previous
//
#include <hip/hip_runtime.h>
#include <hip/hip_bf16.h>
#include <math.h>

#define D_MODEL 2048
#define N_LAYERS 2
#define ED 4096
#define D_STATE 16
#define D_CONV 4
#define DT_RANK 128
#define N_HEADS 4
#define HEAD_DIM 512
#define BATCH 4
#define SEQL 256

typedef __bf16 bf16_t;
typedef bf16_t bf16x8 __attribute__((ext_vector_type(8)));
typedef float f32x4 __attribute__((ext_vector_type(4)));

// ---------------------------------------------------------------- utilities
__device__ __forceinline__ float warp_reduce_sum(float v) {
#pragma unroll
    for (int off = 1; off < 64; off <<= 1) v += __shfl_xor(v, off);
    return v;
}
__device__ __forceinline__ float warp_reduce_max(float v) {
#pragma unroll
    for (int off = 1; off < 64; off <<= 1) v = fmaxf(v, __shfl_xor(v, off));
    return v;
}

__device__ __forceinline__ void gload_lds16(const bf16_t* g, bf16_t* l) {
    __builtin_amdgcn_global_load_lds(
        (const __attribute__((address_space(1))) unsigned int*)g,
        (__attribute__((address_space(3))) unsigned int*)l, 16, 0, 0);
}

// ---------------------------------------------------------------- copy
__global__ void copy_kernel(const float* __restrict__ src, float* __restrict__ dst, int n) {
    int i = blockIdx.x * blockDim.x + threadIdx.x;
    if (i < n) dst[i] = src[i];
}

// f32 -> bf16 convert
__global__ void f2b_kernel(const float* __restrict__ src, bf16_t* __restrict__ dst, int n) {
    int i = blockIdx.x * blockDim.x + threadIdx.x;
    if (i < n) dst[i] = (bf16_t)src[i];
}

// pack dt columns (dbc[:, :128]) into contiguous bf16 [1024][128]
__global__ void dt_pack_kernel(const float* __restrict__ dbc, bf16_t* __restrict__ dt) {
    int i = blockIdx.x * blockDim.x + threadIdx.x;  // < 1024*128
    int row = i >> 7, col = i & 127;
    dt[i] = (bf16_t)dbc[row * (DT_RANK + 2 * D_STATE) + col];
}

// sum split-K partials
__global__ void ksum_kernel(const float* __restrict__ part, float* __restrict__ out, int n,
                            int nz, long stride) {
    int i = blockIdx.x * blockDim.x + threadIdx.x;
    if (i >= n) return;
    float s = 0.f;
    for (int z = 0; z < nz; ++z) s += part[(long)z * stride + i];
    out[i] = s;
}

// ---------------------------------------------------------------- rmsnorm (bf16 out)
__global__ void rmsnorm_kernel(const float* __restrict__ x, const float* __restrict__ w,
                               bf16_t* __restrict__ o) {
    int row = blockIdx.x;
    int tid = threadIdx.x;  // 256
    const float* xr = x + (long)row * D_MODEL;
    float ss = 0.f;
    for (int i = tid; i < D_MODEL; i += 256) { float v = xr[i]; ss += v * v; }
    ss = warp_reduce_sum(ss);
    __shared__ float r[4];
    int wave = tid >> 6;
    if ((tid & 63) == 0) r[wave] = ss;
    __syncthreads();
    float tot = r[0] + r[1] + r[2] + r[3];
    float sc = rsqrtf(tot / (float)D_MODEL + 1e-5f);
    bf16_t* orow = o + (long)row * D_MODEL;
    for (int i = tid; i < D_MODEL; i += 256) orow[i] = (bf16_t)(xr[i] * sc * w[i]);
}

// ---------------------------------------------------------------- bf16 MFMA GEMM (fp32 B weights)
// C[M=1024, N] = A[1024, K](bf16, lda) * B[N, K](fp32, ldb)^T
__global__ __launch_bounds__(256, 2) void gemm_bf16(
    const bf16_t* __restrict__ A, int lda, const float* __restrict__ B, int ldb,
    float* __restrict__ C, int ldc, int N, int K_len, const float* __restrict__ bias,
    int accumulate, int out_bf16, long partial_stride) {
    __shared__ bf16_t As[128 * 32];
    __shared__ bf16_t Bs[128 * 32];
    const int tid = threadIdx.x;
    const int lane = tid & 63;
    const int wave = tid >> 6;
    const int m0 = blockIdx.y * 128;
    const int n0 = blockIdx.x * 128;
    const int kbeg = blockIdx.z * K_len;

    const int cA = wave * 2;
    const bf16_t* gA0 = A + (long)(m0 + cA * 16 + (lane >> 2)) * lda + kbeg + (lane & 3) * 8;
    const bf16_t* gA1 = gA0 + 16L * lda;
    bf16_t* lA0 = &As[cA * 512];
    bf16_t* lA1 = &As[cA * 512 + 512];

    const int brow = tid >> 1;
    const int bcol = (tid & 1) * 16;
    const bool bvalid = (n0 + brow) < N;
    const float* gB = B + (long)(n0 + brow) * ldb + kbeg + bcol;
    bf16_t* lB = &Bs[brow * 32 + bcol];

    const int wr = wave >> 1, wc = wave & 1;
    const int fr = lane & 15, fq = lane >> 4;
    const bf16_t* aBase = &As[(wr * 64 + fr) * 32 + fq * 8];
    const bf16_t* bBase = &Bs[(wc * 64 + fr) * 32 + fq * 8];

    f32x4 acc[4][4] = {};

    for (int kk = 0; kk < K_len; kk += 32) {
        gload_lds16(gA0, lA0);
        gload_lds16(gA1, lA1);
        gA0 += 32;
        gA1 += 32;
        if (bvalid) {
            float4 v0 = *(const float4*)(gB);
            float4 v1 = *(const float4*)(gB + 4);
            float4 v2 = *(const float4*)(gB + 8);
            float4 v3 = *(const float4*)(gB + 12);
            gB += 32;
            bf16x8 p0, p1;
            p0[0] = (bf16_t)v0.x; p0[1] = (bf16_t)v0.y; p0[2] = (bf16_t)v0.z; p0[3] = (bf16_t)v0.w;
            p0[4] = (bf16_t)v1.x; p0[5] = (bf16_t)v1.y; p0[6] = (bf16_t)v1.z; p0[7] = (bf16_t)v1.w;
            p1[0] = (bf16_t)v2.x; p1[1] = (bf16_t)v2.y; p1[2] = (bf16_t)v2.z; p1[3] = (bf16_t)v2.w;
            p1[4] = (bf16_t)v3.x; p1[5] = (bf16_t)v3.y; p1[6] = (bf16_t)v3.z; p1[7] = (bf16_t)v3.w;
            *(bf16x8*)lB = p0;
            *((bf16x8*)lB + 1) = p1;
        }
        __syncthreads();
        bf16x8 af[4], bfr[4];
#pragma unroll
        for (int m = 0; m < 4; ++m) af[m] = *(const bf16x8*)(aBase + m * 512);
#pragma unroll
        for (int n = 0; n < 4; ++n) bfr[n] = *(const bf16x8*)(bBase + n * 512);
#pragma unroll
        for (int m = 0; m < 4; ++m)
#pragma unroll
            for (int n = 0; n < 4; ++n)
                acc[m][n] = __builtin_amdgcn_mfma_f32_16x16x32_bf16(af[m], bfr[n], acc[m][n], 0, 0, 0);
        __syncthreads();
    }

    float* Cz = C + ((gridDim.z > 1) ? (long)blockIdx.z * partial_stride : 0L);
#pragma unroll
    for (int m = 0; m < 4; ++m) {
        const int grow0 = m0 + wr * 64 + m * 16 + fq * 4;
#pragma unroll
        for (int n = 0; n < 4; ++n) {
            const int gcol = n0 + wc * 64 + n * 16 + fr;
            if (gcol >= N) continue;
            float bv = bias ? bias[gcol] : 0.f;
#pragma unroll
            for (int r = 0; r < 4; ++r) {
                long idx = (long)(grow0 + r) * ldc + gcol;
                float v = acc[m][n][r] + bv;
                if (out_bf16) {
                    ((bf16_t*)Cz)[idx] = (bf16_t)v;
                } else {
                    if (accumulate) v += Cz[idx];
                    Cz[idx] = v;
                }
            }
        }
    }
}

// ---------------------------------------------------------------- bf16xbf16 batched MFMA GEMM
// per z: C = A(bf16,lda) * B(bf16,ldb)^T ; offsets: (z>>2)*Outer + (z&3)*Inner
// M,N multiples of 128; K multiple of 32.
__global__ __launch_bounds__(256, 2) void gemm_bb(
    const bf16_t* __restrict__ A, long aO, long aI, int lda,
    const bf16_t* __restrict__ B, long bO, long bI, int ldb,
    void* __restrict__ Cv, long cO, long cI, int ldc,
    int K_len, int out_bf16) {
    __shared__ bf16_t As[128 * 32];
    __shared__ bf16_t Bs[128 * 32];
    const int tid = threadIdx.x;
    const int lane = tid & 63;
    const int wave = tid >> 6;
    const int z = blockIdx.z, zb = z >> 2, zh = z & 3;
    const bf16_t* Az = A + (long)zb * aO + (long)zh * aI;
    const bf16_t* Bz = B + (long)zb * bO + (long)zh * bI;
    const int m0 = blockIdx.y * 128;
    const int n0 = blockIdx.x * 128;

    const int cA = wave * 2;
    const bf16_t* gA0 = Az + (long)(m0 + cA * 16 + (lane >> 2)) * lda + (lane & 3) * 8;
    const bf16_t* gA1 = gA0 + 16L * lda;
    const bf16_t* gB0 = Bz + (long)(n0 + cA * 16 + (lane >> 2)) * ldb + (lane & 3) * 8;
    const bf16_t* gB1 = gB0 + 16L * ldb;
    bf16_t* lA0 = &As[cA * 512];
    bf16_t* lA1 = lA0 + 512;
    bf16_t* lB0 = &Bs[cA * 512];
    bf16_t* lB1 = lB0 + 512;

    const int wr = wave >> 1, wc = wave & 1;
    const int fr = lane & 15, fq = lane >> 4;
    const bf16_t* aBase = &As[(wr * 64 + fr) * 32 + fq * 8];
    const bf16_t* bBase = &Bs[(wc * 64 + fr) * 32 + fq * 8];

    f32x4 acc[4][4] = {};

    for (int kk = 0; kk < K_len; kk += 32) {
        gload_lds16(gA0, lA0);
        gload_lds16(gA1, lA1);
        gload_lds16(gB0, lB0);
        gload_lds16(gB1, lB1);
        gA0 += 32; gA1 += 32; gB0 += 32; gB1 += 32;
        __syncthreads();
        bf16x8 af[4], bfr[4];
#pragma unroll
        for (int m = 0; m < 4; ++m) af[m] = *(const bf16x8*)(aBase + m * 512);
#pragma unroll
        for (int n = 0; n < 4; ++n) bfr[n] = *(const bf16x8*)(bBase + n * 512);
#pragma unroll
        for (int m = 0; m < 4; ++m)
#pragma unroll
            for (int n = 0; n < 4; ++n)
                acc[m][n] = __builtin_amdgcn_mfma_f32_16x16x32_bf16(af[m], bfr[n], acc[m][n], 0, 0, 0);
        __syncthreads();
    }

#pragma unroll
    for (int m = 0; m < 4; ++m) {
        const int grow0 = m0 + wr * 64 + m * 16 + fq * 4;
#pragma unroll
        for (int n = 0; n < 4; ++n) {
            const int gcol = n0 + wc * 64 + n * 16 + fr;
#pragma unroll
            for (int r = 0; r < 4; ++r) {
                long idx = (long)(grow0 + r) * ldc + gcol;
                if (out_bf16) {
                    bf16_t* Cb = (bf16_t*)Cv + (long)zb * cO + (long)zh * cI;
                    Cb[idx] = (bf16_t)acc[m][n][r];
                } else {
                    float* Cf = (float*)Cv + (long)zb * cO + (long)zh * cI;
                    Cf[idx] = acc[m][n][r];
                }
            }
        }
    }
}

// ---------------------------------------------------------------- V transpose: VT[z][d][k] = V[b,k,h,d]
__global__ void vtrans_kernel(const bf16_t* __restrict__ qkvb, bf16_t* __restrict__ vt) {
    int z = blockIdx.z;  // b*4+h
    int b = z >> 2, h = z & 3;
    int d0 = blockIdx.x * 64, k0 = blockIdx.y * 64;
    __shared__ bf16_t tile[64][72];
    int t = threadIdx.x;  // 256
    int r = t >> 2;
    int c4 = (t & 3) * 16;
    const bf16_t* src = qkvb + ((long)(b * SEQL + k0 + r)) * (3 * D_MODEL) + 2 * D_MODEL +
                        h * HEAD_DIM + d0 + c4;
    bf16x8 v0 = *(const bf16x8*)src;
    bf16x8 v1 = *(const bf16x8*)(src + 8);
#pragma unroll
    for (int j = 0; j < 8; ++j) tile[r][c4 + j] = v0[j];
#pragma unroll
    for (int j = 0; j < 8; ++j) tile[r][c4 + 8 + j] = v1[j];
    __syncthreads();
    int dd = t >> 2, kc = (t & 3) * 16;
    bf16_t* dst = vt + (long)z * (HEAD_DIM * SEQL) + (long)(d0 + dd) * SEQL + k0 + kc;
    bf16x8 o0, o1;
#pragma unroll
    for (int j = 0; j < 8; ++j) o0[j] = tile[kc + j][dd];
#pragma unroll
    for (int j = 0; j < 8; ++j) o1[j] = tile[kc + 8 + j][dd];
    *(bf16x8*)dst = o0;
    *(bf16x8*)(dst + 8) = o1;
}

// ---------------------------------------------------------------- softmax rows of S (scale folded)
__global__ void softmax_kernel(const float* __restrict__ S, bf16_t* __restrict__ P) {
    long row = blockIdx.x;  // 4096 = (b,h,q)
    int tid = threadIdx.x;  // 256
    float s = S[row * SEQL + tid] * 0.044194173824159216f;  // 1/sqrt(512)
    __shared__ float red[4];
    float m = warp_reduce_max(s);
    if ((tid & 63) == 0) red[tid >> 6] = m;
    __syncthreads();
    float gm = fmaxf(fmaxf(red[0], red[1]), fmaxf(red[2], red[3]));
    __syncthreads();
    float p = __expf(s - gm);
    float su = warp_reduce_sum(p);
    if ((tid & 63) == 0) red[tid >> 6] = su;
    __syncthreads();
    float gs = red[0] + red[1] + red[2] + red[3];
    P[row * SEQL + tid] = (bf16_t)(p / gs);
}

// ---------------------------------------------------------------- depthwise causal conv + silu
__global__ void conv_silu_kernel(const bf16_t* __restrict__ xzb, const float* __restrict__ cw,
                                 const float* __restrict__ cb, bf16_t* __restrict__ xcb) {
    long idx = (long)blockIdx.x * blockDim.x + threadIdx.x;  // B*L*ED
    int e = idx & (ED - 1);
    long bl = idx >> 12;
    int l = bl & (SEQL - 1);
    float acc = cb[e];
#pragma unroll
    for (int j = 0; j < D_CONV; ++j) {
        int ll = l - (D_CONV - 1) + j;
        if (ll >= 0) acc += cw[e * D_CONV + j] * (float)xzb[(bl + (ll - l)) * (2 * ED) + e];
    }
    float s = acc / (1.f + __expf(-acc));
    xcb[idx] = (bf16_t)s;
}

// ---------------------------------------------------------------- softplus(delta + bias), fp32
__global__ void softplus_kernel(float* __restrict__ delta, const float* __restrict__ dt_b) {
    long idx = (long)blockIdx.x * blockDim.x + threadIdx.x;
    int e = idx & (ED - 1);
    float v = delta[idx] + dt_b[e];
    delta[idx] = (v > 20.f) ? v : log1pf(__expf(v));
}

// ---------------------------------------------------------------- selective scan
__global__ void scan_kernel(const float* __restrict__ delta, const float* __restrict__ dbc,
                            const bf16_t* __restrict__ xcb, const bf16_t* __restrict__ xzb,
                            const float* __restrict__ A_log, const float* __restrict__ Dp,
                            bf16_t* __restrict__ y) {
    int t = blockIdx.x * blockDim.x + threadIdx.x;  // B*ED
    int e = t & (ED - 1);
    int b = t >> 12;
    float Ar[D_STATE], h[D_STATE];
#pragma unroll
    for (int n = 0; n < D_STATE; ++n) {
        Ar[n] = -__expf(A_log[(long)e * D_STATE + n]);
        h[n] = 0.f;
    }
    float dpe = Dp[e];
    for (int l = 0; l < SEQL; ++l) {
        long bl = (long)b * SEQL + l;
        float d = delta[bl * ED + e];
        float x = (float)xcb[bl * ED + e];
        float z = (float)xzb[bl * (2 * ED) + ED + e];
        const float* bc = dbc + bl * (DT_RANK + 2 * D_STATE) + DT_RANK;
        float yacc = 0.f;
        float dx = d * x;
#pragma unroll
        for (int n = 0; n < D_STATE; ++n) {
            float dA = __expf(d * Ar[n]);
            h[n] = dA * h[n] + dx * bc[n];
            yacc += h[n] * bc[D_STATE + n];
        }
        float yv = yacc + x * dpe;
        float zs = z / (1.f + __expf(-z));
        y[bl * ED + e] = (bf16_t)(yv * zs);
    }
}

// ---------------------------------------------------------------- head GEMV1: hm1[b,n] = last[b]·w1[n] + b1[n]
__global__ void head_gemv1(const float* __restrict__ H, const float* __restrict__ w1,
                           const float* __restrict__ b1, float* __restrict__ hm1) {
    int b = blockIdx.y;
    int wave = threadIdx.x >> 6, lane = threadIdx.x & 63;
    int n = blockIdx.x * 4 + wave;
    const float* last = H + ((long)(b * SEQL + SEQL - 1)) * D_MODEL;
    const float* wr = w1 + (long)n * D_MODEL;
    float s = 0.f;
    for (int j = lane * 4; j < D_MODEL; j += 256) {
        float4 a = *(const float4*)(last + j);
        float4 w = *(const float4*)(wr + j);
        s += a.x * w.x + a.y * w.y + a.z * w.z + a.w * w.w;
    }
    s = warp_reduce_sum(s);
    if (lane == 0) hm1[b * 1024 + n] = s + b1[n];
}

// ---------------------------------------------------------------- head final: LN + ELU + w2 + normalize
__global__ void head_final(const float* __restrict__ hm1, const float* __restrict__ ln_g,
                           const float* __restrict__ ln_b, const float* __restrict__ w2,
                           const float* __restrict__ b2, float* __restrict__ out) {
    int b = blockIdx.x;
    int tid = threadIdx.x;  // 1024
    __shared__ float hm[1024];
    __shared__ float r1[16], r2[16];
    __shared__ float stats[2];
    __shared__ float outs[64];

    float v = hm1[b * 1024 + tid];
    float s1 = warp_reduce_sum(v);
    float s2 = warp_reduce_sum(v * v);
    int wave = tid >> 6;
    if ((tid & 63) == 0) { r1[wave] = s1; r2[wave] = s2; }
    __syncthreads();
    if (tid == 0) {
        float t1 = 0.f, t2 = 0.f;
        for (int w = 0; w < 16; ++w) { t1 += r1[w]; t2 += r2[w]; }
        float mean = t1 / 1024.f;
        stats[0] = mean;
        stats[1] = rsqrtf(t2 / 1024.f - mean * mean + 1e-5f);
    }
    __syncthreads();
    float x = (v - stats[0]) * stats[1] * ln_g[tid] + ln_b[tid];
    x = (x > 0.f) ? x : (__expf(x) - 1.f);
    hm[tid] = x;
    __syncthreads();

    int o = tid >> 4, kk = tid & 15;
    float a = 0.f;
    const float* w2r = w2 + (long)o * 1024;
    for (int j = kk; j < 1024; j += 16) a += hm[j] * w2r[j];
#pragma unroll
    for (int off = 1; off < 16; off <<= 1) a += __shfl_xor(a, off);
    if (kk == 0) outs[o] = a + b2[o];
    __syncthreads();
    if (tid < 64) {
        float vv = outs[tid];
        float ss = warp_reduce_sum(vv * vv);
        out[b * 64 + tid] = vv / fmaxf(sqrtf(ss), 1e-12f);
    }
}

// ---------------------------------------------------------------- launch
extern "C" void kernel_launch(void* const* d_in, const int* in_sizes, int n_in,
                              void* d_out, int out_size, void* d_ws, size_t ws_size,
                              hipStream_t stream) {
    const float* x = (const float*)d_in[0];
    const float* norm_w = (const float*)d_in[1];
    const float* in_proj_w = (const float*)d_in[2];
    const float* conv_w = (const float*)d_in[3];
    const float* conv_b = (const float*)d_in[4];
    const float* x_proj_w = (const float*)d_in[5];
    const float* dt_proj_w = (const float*)d_in[6];
    const float* dt_proj_b = (const float*)d_in[7];
    const float* A_log = (const float*)d_in[8];
    const float* D_param = (const float*)d_in[9];
    const float* out_proj_w = (const float*)d_in[10];
    const float* attn_in_w = (const float*)d_in[11];
    const float* attn_in_b = (const float*)d_in[12];
    const float* attn_out_w = (const float*)d_in[13];
    const float* attn_out_b = (const float*)d_in[14];
    const float* w1 = (const float*)d_in[15];
    const float* b1 = (const float*)d_in[16];
    const float* ln_g = (const float*)d_in[17];
    const float* ln_b = (const float*)d_in[18];
    const float* w2 = (const float*)d_in[19];
    const float* b2 = (const float*)d_in[20];

    float* ws = (float*)d_ws;
    size_t o = 0;
    float* H = ws + o;      o += 2097152;       // (B,L,D) fp32
    float* SCR = ws + o;    o += 6291456;       // XZb bf16 / attention-phase buffers
    float* DELTA = ws + o;  o += 4194304;       // (B,L,ED) fp32
    float* DBC = ws + o;    o += 163840;        // (B,L,160) fp32
    float* XPART = ws + o;  o += 1310720;       // 8 x (1024,160) split-K partials
    bf16_t* XNb = (bf16_t*)(ws + o);  o += 1048576;  // (B,L,D) bf16
    bf16_t* XCb = (bf16_t*)(ws + o);  o += 2097152;  // (B,L,ED) bf16
    bf16_t* DTb = (bf16_t*)(ws + o);  o += 65536;    // (1024,128) bf16
    bf16_t* Yb = (bf16_t*)(ws + o);   o += 2097152;  // (B,L,ED) bf16
    bf16_t* Hb = (bf16_t*)(ws + o);   o += 1048576;  // (B,L,D) bf16
    bf16_t* AOb = (bf16_t*)(ws + o);  o += 1048576;  // (B,L,D) bf16
    float* HM1 = ws + o;    o += 4096;          // (B,1024) fp32

    bf16_t* XZb = (bf16_t*)SCR;
    // attention-phase aliases inside SCR (XZb dead by then)
    bf16_t* QKVb = (bf16_t*)SCR;                       // 1024x6144 bf16 = 3,145,728 words
    float* SBUF = SCR + 3145728;                       // 16x256x256 fp32 = 1,048,576 words
    bf16_t* Pb = (bf16_t*)(SCR + 3145728 + 1048576);   // 1M bf16 = 524,288 words
    bf16_t* VTb = (bf16_t*)(SCR + 3145728 + 1048576 + 524288);  // 2M bf16 = 1,048,576 words

    const int M = BATCH * SEQL;  // 1024
    const long S_H = (long)M * D_MODEL;
    const long S_XC = (long)M * ED;

    copy_kernel<<<(S_H + 255) / 256, 256, 0, stream>>>(x, H, (int)S_H);

    for (int i = 0; i < N_LAYERS; ++i) {
        rmsnorm_kernel<<<M, 256, 0, stream>>>(H, norm_w + (long)i * D_MODEL, XNb);
        gemm_bf16<<<dim3(64, 8, 1), 256, 0, stream>>>(
            XNb, D_MODEL, in_proj_w + (long)i * 2 * ED * D_MODEL, D_MODEL, (float*)XZb, 2 * ED,
            2 * ED, D_MODEL, nullptr, 0, 1, 0);
        conv_silu_kernel<<<(S_XC + 255) / 256, 256, 0, stream>>>(
            XZb, conv_w + (long)i * ED * D_CONV, conv_b + (long)i * ED, XCb);
        gemm_bf16<<<dim3(2, 8, 8), 256, 0, stream>>>(
            XCb, ED, x_proj_w + (long)i * (DT_RANK + 2 * D_STATE) * ED, ED, XPART,
            DT_RANK + 2 * D_STATE, DT_RANK + 2 * D_STATE, ED / 8, nullptr, 0, 0,
            (long)M * (DT_RANK + 2 * D_STATE));
        ksum_kernel<<<640, 256, 0, stream>>>(XPART, DBC, M * (DT_RANK + 2 * D_STATE), 8,
                                             (long)M * (DT_RANK + 2 * D_STATE));
        dt_pack_kernel<<<512, 256, 0, stream>>>(DBC, DTb);
        gemm_bf16<<<dim3(32, 8, 1), 256, 0, stream>>>(
            DTb, DT_RANK, dt_proj_w + (long)i * ED * DT_RANK, DT_RANK, DELTA, ED, ED, DT_RANK,
            nullptr, 0, 0, 0);
        softplus_kernel<<<(S_XC + 255) / 256, 256, 0, stream>>>(DELTA, dt_proj_b + (long)i * ED);
        scan_kernel<<<(BATCH * ED) / 64, 64, 0, stream>>>(
            DELTA, DBC, XCb, XZb, A_log + (long)i * ED * D_STATE, D_param + (long)i * ED, Yb);
        gemm_bf16<<<dim3(16, 8, 1), 256, 0, stream>>>(
            Yb, ED, out_proj_w + (long)i * D_MODEL * ED, ED, H, D_MODEL, D_MODEL, ED, nullptr, 1,
            0, 0);
    }

    f2b_kernel<<<(int)((S_H + 255) / 256), 256, 0, stream>>>(H, Hb, (int)S_H);
    // qkv = H @ attn_in_w^T + b  -> bf16
    gemm_bf16<<<dim3(48, 8, 1), 256, 0, stream>>>(Hb, D_MODEL, attn_in_w, D_MODEL, (float*)QKVb,
                                                  3 * D_MODEL, 3 * D_MODEL, D_MODEL, attn_in_b, 0,
                                                  1, 0);
    // V transpose: VT[z][d][k]
    vtrans_kernel<<<dim3(8, 4, 16), 256, 0, stream>>>(QKVb, VTb);
    // scores: S[z][q][k] = Q·K^T (batched)
    gemm_bb<<<dim3(2, 2, 16), 256, 0, stream>>>(
        QKVb, (long)SEQL * 3 * D_MODEL, HEAD_DIM, 3 * D_MODEL,
        QKVb + D_MODEL, (long)SEQL * 3 * D_MODEL, HEAD_DIM, 3 * D_MODEL,
        SBUF, 4L * SEQL * SEQL, (long)SEQL * SEQL, SEQL, HEAD_DIM, 0);
    softmax_kernel<<<BATCH * N_HEADS * SEQL, 256, 0, stream>>>(SBUF, Pb);
    // AO[q, h*512+d] = P·VT^T (batched), bf16 out strided into AOb
    gemm_bb<<<dim3(4, 2, 16), 256, 0, stream>>>(
        Pb, 4L * SEQL * SEQL, (long)SEQL * SEQL, SEQL,
        VTb, 4L * HEAD_DIM * SEQL, (long)HEAD_DIM * SEQL, SEQL,
        AOb, (long)SEQL * D_MODEL, HEAD_DIM, D_MODEL, SEQL, 1);
    // H += AO @ attn_out_w^T + b
    gemm_bf16<<<dim3(16, 8, 1), 256, 0, stream>>>(AOb, D_MODEL, attn_out_w, D_MODEL, H, D_MODEL,
                                                  D_MODEL, D_MODEL, attn_out_b, 1, 0, 0);

    head_gemv1<<<dim3(256, 4), 256, 0, stream>>>(H, w1, b1, HM1);
    head_final<<<BATCH, 1024, 0, stream>>>(HM1, ln_g, ln_b, w2, b2, (float*)d_out);
}

// Round 4
// 1332.067 us; speedup vs baseline: 4.1427x; 1.0531x over previous
//
#include <hip/hip_runtime.h>
#include <hip/hip_bf16.h>
#include <math.h>

#define D_MODEL 2048
#define N_LAYERS 2
#define ED 4096
#define D_STATE 16
#define D_CONV 4
#define DT_RANK 128
#define N_HEADS 4
#define HEAD_DIM 512
#define BATCH 4
#define SEQL 256

typedef __bf16 bf16_t;
typedef bf16_t bf16x8 __attribute__((ext_vector_type(8)));
typedef float f32x4 __attribute__((ext_vector_type(4)));

// ---------------------------------------------------------------- utilities
__device__ __forceinline__ float warp_reduce_sum(float v) {
#pragma unroll
    for (int off = 1; off < 64; off <<= 1) v += __shfl_xor(v, off);
    return v;
}
__device__ __forceinline__ float warp_reduce_max(float v) {
#pragma unroll
    for (int off = 1; off < 64; off <<= 1) v = fmaxf(v, __shfl_xor(v, off));
    return v;
}

__device__ __forceinline__ void gload_lds16(const bf16_t* g, bf16_t* l) {
    __builtin_amdgcn_global_load_lds(
        (const __attribute__((address_space(1))) unsigned int*)g,
        (__attribute__((address_space(3))) unsigned int*)l, 16, 0, 0);
}

// ---------------------------------------------------------------- copy
__global__ void copy_kernel(const float* __restrict__ src, float* __restrict__ dst, int n) {
    int i = blockIdx.x * blockDim.x + threadIdx.x;
    if (i < n) dst[i] = src[i];
}

// f32 -> bf16 convert
__global__ void f2b_kernel(const float* __restrict__ src, bf16_t* __restrict__ dst, int n) {
    int i = blockIdx.x * blockDim.x + threadIdx.x;
    if (i < n) dst[i] = (bf16_t)src[i];
}

// pack dt columns (dbc[:, :128]) into contiguous bf16 [1024][128]
__global__ void dt_pack_kernel(const float* __restrict__ dbc, bf16_t* __restrict__ dt) {
    int i = blockIdx.x * blockDim.x + threadIdx.x;  // < 1024*128
    int row = i >> 7, col = i & 127;
    dt[i] = (bf16_t)dbc[row * (DT_RANK + 2 * D_STATE) + col];
}

// sum split-K partials
__global__ void ksum_kernel(const float* __restrict__ part, float* __restrict__ out, int n,
                            int nz, long stride) {
    int i = blockIdx.x * blockDim.x + threadIdx.x;
    if (i >= n) return;
    float s = 0.f;
    for (int z = 0; z < nz; ++z) s += part[(long)z * stride + i];
    out[i] = s;
}

// ---------------------------------------------------------------- rmsnorm (bf16 out)
__global__ void rmsnorm_kernel(const float* __restrict__ x, const float* __restrict__ w,
                               bf16_t* __restrict__ o) {
    int row = blockIdx.x;
    int tid = threadIdx.x;  // 256
    const float* xr = x + (long)row * D_MODEL;
    float ss = 0.f;
    for (int i = tid; i < D_MODEL; i += 256) { float v = xr[i]; ss += v * v; }
    ss = warp_reduce_sum(ss);
    __shared__ float r[4];
    int wave = tid >> 6;
    if ((tid & 63) == 0) r[wave] = ss;
    __syncthreads();
    float tot = r[0] + r[1] + r[2] + r[3];
    float sc = rsqrtf(tot / (float)D_MODEL + 1e-5f);
    bf16_t* orow = o + (long)row * D_MODEL;
    for (int i = tid; i < D_MODEL; i += 256) orow[i] = (bf16_t)(xr[i] * sc * w[i]);
}

// ---------------------------------------------------------------- bf16 MFMA GEMM (fp32 B weights)
// C[M=1024, N] = A[1024, K](bf16, lda) * B[N, K](fp32, ldb)^T
__global__ __launch_bounds__(256, 2) void gemm_bf16(
    const bf16_t* __restrict__ A, int lda, const float* __restrict__ B, int ldb,
    float* __restrict__ C, int ldc, int N, int K_len, const float* __restrict__ bias,
    int accumulate, int out_bf16, long partial_stride) {
    __shared__ bf16_t As[128 * 32];
    __shared__ bf16_t Bs[128 * 32];
    const int tid = threadIdx.x;
    const int lane = tid & 63;
    const int wave = tid >> 6;
    const int m0 = blockIdx.y * 128;
    const int n0 = blockIdx.x * 128;
    const int kbeg = blockIdx.z * K_len;

    const int cA = wave * 2;
    const bf16_t* gA0 = A + (long)(m0 + cA * 16 + (lane >> 2)) * lda + kbeg + (lane & 3) * 8;
    const bf16_t* gA1 = gA0 + 16L * lda;
    bf16_t* lA0 = &As[cA * 512];
    bf16_t* lA1 = &As[cA * 512 + 512];

    const int brow = tid >> 1;
    const int bcol = (tid & 1) * 16;
    const bool bvalid = (n0 + brow) < N;
    const float* gB = B + (long)(n0 + brow) * ldb + kbeg + bcol;
    bf16_t* lB = &Bs[brow * 32 + bcol];

    const int wr = wave >> 1, wc = wave & 1;
    const int fr = lane & 15, fq = lane >> 4;
    const bf16_t* aBase = &As[(wr * 64 + fr) * 32 + fq * 8];
    const bf16_t* bBase = &Bs[(wc * 64 + fr) * 32 + fq * 8];

    f32x4 acc[4][4] = {};

    for (int kk = 0; kk < K_len; kk += 32) {
        gload_lds16(gA0, lA0);
        gload_lds16(gA1, lA1);
        gA0 += 32;
        gA1 += 32;
        if (bvalid) {
            float4 v0 = *(const float4*)(gB);
            float4 v1 = *(const float4*)(gB + 4);
            float4 v2 = *(const float4*)(gB + 8);
            float4 v3 = *(const float4*)(gB + 12);
            gB += 32;
            bf16x8 p0, p1;
            p0[0] = (bf16_t)v0.x; p0[1] = (bf16_t)v0.y; p0[2] = (bf16_t)v0.z; p0[3] = (bf16_t)v0.w;
            p0[4] = (bf16_t)v1.x; p0[5] = (bf16_t)v1.y; p0[6] = (bf16_t)v1.z; p0[7] = (bf16_t)v1.w;
            p1[0] = (bf16_t)v2.x; p1[1] = (bf16_t)v2.y; p1[2] = (bf16_t)v2.z; p1[3] = (bf16_t)v2.w;
            p1[4] = (bf16_t)v3.x; p1[5] = (bf16_t)v3.y; p1[6] = (bf16_t)v3.z; p1[7] = (bf16_t)v3.w;
            *(bf16x8*)lB = p0;
            *((bf16x8*)lB + 1) = p1;
        }
        __syncthreads();
        bf16x8 af[4], bfr[4];
#pragma unroll
        for (int m = 0; m < 4; ++m) af[m] = *(const bf16x8*)(aBase + m * 512);
#pragma unroll
        for (int n = 0; n < 4; ++n) bfr[n] = *(const bf16x8*)(bBase + n * 512);
#pragma unroll
        for (int m = 0; m < 4; ++m)
#pragma unroll
            for (int n = 0; n < 4; ++n)
                acc[m][n] = __builtin_amdgcn_mfma_f32_16x16x32_bf16(af[m], bfr[n], acc[m][n], 0, 0, 0);
        __syncthreads();
    }

    float* Cz = C + ((gridDim.z > 1) ? (long)blockIdx.z * partial_stride : 0L);
#pragma unroll
    for (int m = 0; m < 4; ++m) {
        const int grow0 = m0 + wr * 64 + m * 16 + fq * 4;
#pragma unroll
        for (int n = 0; n < 4; ++n) {
            const int gcol = n0 + wc * 64 + n * 16 + fr;
            if (gcol >= N) continue;
            float bv = bias ? bias[gcol] : 0.f;
#pragma unroll
            for (int r = 0; r < 4; ++r) {
                long idx = (long)(grow0 + r) * ldc + gcol;
                float v = acc[m][n][r] + bv;
                if (out_bf16) {
                    ((bf16_t*)Cz)[idx] = (bf16_t)v;
                } else {
                    if (accumulate) v += Cz[idx];
                    Cz[idx] = v;
                }
            }
        }
    }
}

// ---------------------------------------------------------------- bf16xbf16 batched MFMA GEMM
__global__ __launch_bounds__(256, 2) void gemm_bb(
    const bf16_t* __restrict__ A, long aO, long aI, int lda,
    const bf16_t* __restrict__ B, long bO, long bI, int ldb,
    void* __restrict__ Cv, long cO, long cI, int ldc,
    int K_len, int out_bf16) {
    __shared__ bf16_t As[128 * 32];
    __shared__ bf16_t Bs[128 * 32];
    const int tid = threadIdx.x;
    const int lane = tid & 63;
    const int wave = tid >> 6;
    const int z = blockIdx.z, zb = z >> 2, zh = z & 3;
    const bf16_t* Az = A + (long)zb * aO + (long)zh * aI;
    const bf16_t* Bz = B + (long)zb * bO + (long)zh * bI;
    const int m0 = blockIdx.y * 128;
    const int n0 = blockIdx.x * 128;

    const int cA = wave * 2;
    const bf16_t* gA0 = Az + (long)(m0 + cA * 16 + (lane >> 2)) * lda + (lane & 3) * 8;
    const bf16_t* gA1 = gA0 + 16L * lda;
    const bf16_t* gB0 = Bz + (long)(n0 + cA * 16 + (lane >> 2)) * ldb + (lane & 3) * 8;
    const bf16_t* gB1 = gB0 + 16L * ldb;
    bf16_t* lA0 = &As[cA * 512];
    bf16_t* lA1 = lA0 + 512;
    bf16_t* lB0 = &Bs[cA * 512];
    bf16_t* lB1 = lB0 + 512;

    const int wr = wave >> 1, wc = wave & 1;
    const int fr = lane & 15, fq = lane >> 4;
    const bf16_t* aBase = &As[(wr * 64 + fr) * 32 + fq * 8];
    const bf16_t* bBase = &Bs[(wc * 64 + fr) * 32 + fq * 8];

    f32x4 acc[4][4] = {};

    for (int kk = 0; kk < K_len; kk += 32) {
        gload_lds16(gA0, lA0);
        gload_lds16(gA1, lA1);
        gload_lds16(gB0, lB0);
        gload_lds16(gB1, lB1);
        gA0 += 32; gA1 += 32; gB0 += 32; gB1 += 32;
        __syncthreads();
        bf16x8 af[4], bfr[4];
#pragma unroll
        for (int m = 0; m < 4; ++m) af[m] = *(const bf16x8*)(aBase + m * 512);
#pragma unroll
        for (int n = 0; n < 4; ++n) bfr[n] = *(const bf16x8*)(bBase + n * 512);
#pragma unroll
        for (int m = 0; m < 4; ++m)
#pragma unroll
            for (int n = 0; n < 4; ++n)
                acc[m][n] = __builtin_amdgcn_mfma_f32_16x16x32_bf16(af[m], bfr[n], acc[m][n], 0, 0, 0);
        __syncthreads();
    }

#pragma unroll
    for (int m = 0; m < 4; ++m) {
        const int grow0 = m0 + wr * 64 + m * 16 + fq * 4;
#pragma unroll
        for (int n = 0; n < 4; ++n) {
            const int gcol = n0 + wc * 64 + n * 16 + fr;
#pragma unroll
            for (int r = 0; r < 4; ++r) {
                long idx = (long)(grow0 + r) * ldc + gcol;
                if (out_bf16) {
                    bf16_t* Cb = (bf16_t*)Cv + (long)zb * cO + (long)zh * cI;
                    Cb[idx] = (bf16_t)acc[m][n][r];
                } else {
                    float* Cf = (float*)Cv + (long)zb * cO + (long)zh * cI;
                    Cf[idx] = acc[m][n][r];
                }
            }
        }
    }
}

// ---------------------------------------------------------------- V transpose: VT[z][d][k] = V[b,k,h,d]
__global__ void vtrans_kernel(const bf16_t* __restrict__ qkvb, bf16_t* __restrict__ vt) {
    int z = blockIdx.z;  // b*4+h
    int b = z >> 2, h = z & 3;
    int d0 = blockIdx.x * 64, k0 = blockIdx.y * 64;
    __shared__ bf16_t tile[64][72];
    int t = threadIdx.x;  // 256
    int r = t >> 2;
    int c4 = (t & 3) * 16;
    const bf16_t* src = qkvb + ((long)(b * SEQL + k0 + r)) * (3 * D_MODEL) + 2 * D_MODEL +
                        h * HEAD_DIM + d0 + c4;
    bf16x8 v0 = *(const bf16x8*)src;
    bf16x8 v1 = *(const bf16x8*)(src + 8);
#pragma unroll
    for (int j = 0; j < 8; ++j) tile[r][c4 + j] = v0[j];
#pragma unroll
    for (int j = 0; j < 8; ++j) tile[r][c4 + 8 + j] = v1[j];
    __syncthreads();
    int dd = t >> 2, kc = (t & 3) * 16;
    bf16_t* dst = vt + (long)z * (HEAD_DIM * SEQL) + (long)(d0 + dd) * SEQL + k0 + kc;
    bf16x8 o0, o1;
#pragma unroll
    for (int j = 0; j < 8; ++j) o0[j] = tile[kc + j][dd];
#pragma unroll
    for (int j = 0; j < 8; ++j) o1[j] = tile[kc + 8 + j][dd];
    *(bf16x8*)dst = o0;
    *(bf16x8*)(dst + 8) = o1;
}

// ---------------------------------------------------------------- softmax rows of S (scale folded)
__global__ void softmax_kernel(const float* __restrict__ S, bf16_t* __restrict__ P) {
    long row = blockIdx.x;  // 4096 = (b,h,q)
    int tid = threadIdx.x;  // 256
    float s = S[row * SEQL + tid] * 0.044194173824159216f;  // 1/sqrt(512)
    __shared__ float red[4];
    float m = warp_reduce_max(s);
    if ((tid & 63) == 0) red[tid >> 6] = m;
    __syncthreads();
    float gm = fmaxf(fmaxf(red[0], red[1]), fmaxf(red[2], red[3]));
    __syncthreads();
    float p = __expf(s - gm);
    float su = warp_reduce_sum(p);
    if ((tid & 63) == 0) red[tid >> 6] = su;
    __syncthreads();
    float gs = red[0] + red[1] + red[2] + red[3];
    P[row * SEQL + tid] = (bf16_t)(p / gs);
}

// ---------------------------------------------------------------- depthwise causal conv + silu
__global__ void conv_silu_kernel(const bf16_t* __restrict__ xzb, const float* __restrict__ cw,
                                 const float* __restrict__ cb, bf16_t* __restrict__ xcb) {
    long idx = (long)blockIdx.x * blockDim.x + threadIdx.x;  // B*L*ED
    int e = idx & (ED - 1);
    long bl = idx >> 12;
    int l = bl & (SEQL - 1);
    float acc = cb[e];
#pragma unroll
    for (int j = 0; j < D_CONV; ++j) {
        int ll = l - (D_CONV - 1) + j;
        if (ll >= 0) acc += cw[e * D_CONV + j] * (float)xzb[(bl + (ll - l)) * (2 * ED) + e];
    }
    float s = acc / (1.f + __expf(-acc));
    xcb[idx] = (bf16_t)s;
}

// ---------------------------------------------------------------- softplus(delta + bias), fp32
__global__ void softplus_kernel(float* __restrict__ delta, const float* __restrict__ dt_b) {
    long idx = (long)blockIdx.x * blockDim.x + threadIdx.x;
    int e = idx & (ED - 1);
    float v = delta[idx] + dt_b[e];
    delta[idx] = (v > 20.f) ? v : log1pf(__expf(v));
}

// ---------------------------------------------------------------- selective scan, 16 lanes per (b,e)
// block = 256 threads = 16 groups of 16 lanes; lane n owns state n.
// grid = B * ED/16 = 1024 blocks -> 4096 waves (16/CU)
__global__ __launch_bounds__(256) void scan16_kernel(
    const float* __restrict__ delta, const float* __restrict__ dbc,
    const bf16_t* __restrict__ xcb, const bf16_t* __restrict__ xzb,
    const float* __restrict__ A_log, const float* __restrict__ Dp, bf16_t* __restrict__ y) {
    const int t = threadIdx.x;
    const int n = t & 15;        // state index
    const int g = t >> 4;        // group 0..15
    const int b = blockIdx.x >> 8;
    const int e = (blockIdx.x & 255) * 16 + g;
    const int R = DT_RANK + 2 * D_STATE;  // 160

    const float Ar = -__expf(A_log[(long)e * D_STATE + n]);
    const float dpe = Dp[e];
    float h = 0.f;

    const float* dP = delta + (long)b * SEQL * ED + e;
    const bf16_t* xP = xcb + (long)b * SEQL * ED + e;
    const bf16_t* zP = xzb + (long)b * SEQL * 2 * ED + ED + e;
    const float* bcP = dbc + (long)b * SEQL * R + DT_RANK + n;
    bf16_t* yP = y + (long)b * SEQL * ED + e;

    for (int l = 0; l < SEQL; ++l) {
        float d = dP[(long)l * ED];
        float x = (float)xP[(long)l * ED];
        float bcn = bcP[(long)l * R];
        float bcc = bcP[(long)l * R + D_STATE];
        float dA = __expf(d * Ar);
        h = dA * h + d * x * bcn;
        float p = h * bcc;
        p += __shfl_xor(p, 1);
        p += __shfl_xor(p, 2);
        p += __shfl_xor(p, 4);
        p += __shfl_xor(p, 8);
        if (n == 0) {
            float z = (float)zP[(long)l * 2 * ED];
            float zs = z / (1.f + __expf(-z));
            yP[(long)l * ED] = (bf16_t)((p + x * dpe) * zs);
        }
    }
}

// ---------------------------------------------------------------- head GEMV1
__global__ void head_gemv1(const float* __restrict__ H, const float* __restrict__ w1,
                           const float* __restrict__ b1, float* __restrict__ hm1) {
    int b = blockIdx.y;
    int wave = threadIdx.x >> 6, lane = threadIdx.x & 63;
    int n = blockIdx.x * 4 + wave;
    const float* last = H + ((long)(b * SEQL + SEQL - 1)) * D_MODEL;
    const float* wr = w1 + (long)n * D_MODEL;
    float s = 0.f;
    for (int j = lane * 4; j < D_MODEL; j += 256) {
        float4 a = *(const float4*)(last + j);
        float4 w = *(const float4*)(wr + j);
        s += a.x * w.x + a.y * w.y + a.z * w.z + a.w * w.w;
    }
    s = warp_reduce_sum(s);
    if (lane == 0) hm1[b * 1024 + n] = s + b1[n];
}

// ---------------------------------------------------------------- head final: LN + ELU + w2 + normalize
__global__ void head_final(const float* __restrict__ hm1, const float* __restrict__ ln_g,
                           const float* __restrict__ ln_b, const float* __restrict__ w2,
                           const float* __restrict__ b2, float* __restrict__ out) {
    int b = blockIdx.x;
    int tid = threadIdx.x;  // 1024
    __shared__ float hm[1024];
    __shared__ float r1[16], r2[16];
    __shared__ float stats[2];
    __shared__ float outs[64];

    float v = hm1[b * 1024 + tid];
    float s1 = warp_reduce_sum(v);
    float s2 = warp_reduce_sum(v * v);
    int wave = tid >> 6;
    if ((tid & 63) == 0) { r1[wave] = s1; r2[wave] = s2; }
    __syncthreads();
    if (tid == 0) {
        float t1 = 0.f, t2 = 0.f;
        for (int w = 0; w < 16; ++w) { t1 += r1[w]; t2 += r2[w]; }
        float mean = t1 / 1024.f;
        stats[0] = mean;
        stats[1] = rsqrtf(t2 / 1024.f - mean * mean + 1e-5f);
    }
    __syncthreads();
    float x = (v - stats[0]) * stats[1] * ln_g[tid] + ln_b[tid];
    x = (x > 0.f) ? x : (__expf(x) - 1.f);
    hm[tid] = x;
    __syncthreads();

    int o = tid >> 4, kk = tid & 15;
    float a = 0.f;
    const float* w2r = w2 + (long)o * 1024;
    for (int j = kk; j < 1024; j += 16) a += hm[j] * w2r[j];
#pragma unroll
    for (int off = 1; off < 16; off <<= 1) a += __shfl_xor(a, off);
    if (kk == 0) outs[o] = a + b2[o];
    __syncthreads();
    if (tid < 64) {
        float vv = outs[tid];
        float ss = warp_reduce_sum(vv * vv);
        out[b * 64 + tid] = vv / fmaxf(sqrtf(ss), 1e-12f);
    }
}

// ---------------------------------------------------------------- launch
extern "C" void kernel_launch(void* const* d_in, const int* in_sizes, int n_in,
                              void* d_out, int out_size, void* d_ws, size_t ws_size,
                              hipStream_t stream) {
    const float* x = (const float*)d_in[0];
    const float* norm_w = (const float*)d_in[1];
    const float* in_proj_w = (const float*)d_in[2];
    const float* conv_w = (const float*)d_in[3];
    const float* conv_b = (const float*)d_in[4];
    const float* x_proj_w = (const float*)d_in[5];
    const float* dt_proj_w = (const float*)d_in[6];
    const float* dt_proj_b = (const float*)d_in[7];
    const float* A_log = (const float*)d_in[8];
    const float* D_param = (const float*)d_in[9];
    const float* out_proj_w = (const float*)d_in[10];
    const float* attn_in_w = (const float*)d_in[11];
    const float* attn_in_b = (const float*)d_in[12];
    const float* attn_out_w = (const float*)d_in[13];
    const float* attn_out_b = (const float*)d_in[14];
    const float* w1 = (const float*)d_in[15];
    const float* b1 = (const float*)d_in[16];
    const float* ln_g = (const float*)d_in[17];
    const float* ln_b = (const float*)d_in[18];
    const float* w2 = (const float*)d_in[19];
    const float* b2 = (const float*)d_in[20];

    float* ws = (float*)d_ws;
    size_t o = 0;
    float* H = ws + o;      o += 2097152;       // (B,L,D) fp32
    float* SCR = ws + o;    o += 6291456;       // XZb bf16 / attention-phase buffers
    float* DELTA = ws + o;  o += 4194304;       // (B,L,ED) fp32
    float* DBC = ws + o;    o += 163840;        // (B,L,160) fp32
    float* XPART = ws + o;  o += 1310720;       // 8 x (1024,160) split-K partials
    bf16_t* XNb = (bf16_t*)(ws + o);  o += 1048576;  // (B,L,D) bf16
    bf16_t* XCb = (bf16_t*)(ws + o);  o += 2097152;  // (B,L,ED) bf16
    bf16_t* DTb = (bf16_t*)(ws + o);  o += 65536;    // (1024,128) bf16
    bf16_t* Yb = (bf16_t*)(ws + o);   o += 2097152;  // (B,L,ED) bf16
    bf16_t* Hb = (bf16_t*)(ws + o);   o += 1048576;  // (B,L,D) bf16
    bf16_t* AOb = (bf16_t*)(ws + o);  o += 1048576;  // (B,L,D) bf16
    float* HM1 = ws + o;    o += 4096;          // (B,1024) fp32

    bf16_t* XZb = (bf16_t*)SCR;
    bf16_t* QKVb = (bf16_t*)SCR;                       // 1024x6144 bf16
    float* SBUF = SCR + 3145728;                       // 16x256x256 fp32
    bf16_t* Pb = (bf16_t*)(SCR + 3145728 + 1048576);   // 16x256x256 bf16
    bf16_t* VTb = (bf16_t*)(SCR + 3145728 + 1048576 + 524288);  // 16x512x256 bf16

    const int M = BATCH * SEQL;  // 1024
    const long S_H = (long)M * D_MODEL;
    const long S_XC = (long)M * ED;

    copy_kernel<<<(S_H + 255) / 256, 256, 0, stream>>>(x, H, (int)S_H);

    for (int i = 0; i < N_LAYERS; ++i) {
        rmsnorm_kernel<<<M, 256, 0, stream>>>(H, norm_w + (long)i * D_MODEL, XNb);
        gemm_bf16<<<dim3(64, 8, 1), 256, 0, stream>>>(
            XNb, D_MODEL, in_proj_w + (long)i * 2 * ED * D_MODEL, D_MODEL, (float*)XZb, 2 * ED,
            2 * ED, D_MODEL, nullptr, 0, 1, 0);
        conv_silu_kernel<<<(S_XC + 255) / 256, 256, 0, stream>>>(
            XZb, conv_w + (long)i * ED * D_CONV, conv_b + (long)i * ED, XCb);
        gemm_bf16<<<dim3(2, 8, 8), 256, 0, stream>>>(
            XCb, ED, x_proj_w + (long)i * (DT_RANK + 2 * D_STATE) * ED, ED, XPART,
            DT_RANK + 2 * D_STATE, DT_RANK + 2 * D_STATE, ED / 8, nullptr, 0, 0,
            (long)M * (DT_RANK + 2 * D_STATE));
        ksum_kernel<<<640, 256, 0, stream>>>(XPART, DBC, M * (DT_RANK + 2 * D_STATE), 8,
                                             (long)M * (DT_RANK + 2 * D_STATE));
        dt_pack_kernel<<<512, 256, 0, stream>>>(DBC, DTb);
        gemm_bf16<<<dim3(32, 8, 1), 256, 0, stream>>>(
            DTb, DT_RANK, dt_proj_w + (long)i * ED * DT_RANK, DT_RANK, DELTA, ED, ED, DT_RANK,
            nullptr, 0, 0, 0);
        softplus_kernel<<<(S_XC + 255) / 256, 256, 0, stream>>>(DELTA, dt_proj_b + (long)i * ED);
        scan16_kernel<<<BATCH * (ED / 16), 256, 0, stream>>>(
            DELTA, DBC, XCb, XZb, A_log + (long)i * ED * D_STATE, D_param + (long)i * ED, Yb);
        gemm_bf16<<<dim3(16, 8, 1), 256, 0, stream>>>(
            Yb, ED, out_proj_w + (long)i * D_MODEL * ED, ED, H, D_MODEL, D_MODEL, ED, nullptr, 1,
            0, 0);
    }

    f2b_kernel<<<(int)((S_H + 255) / 256), 256, 0, stream>>>(H, Hb, (int)S_H);
    gemm_bf16<<<dim3(48, 8, 1), 256, 0, stream>>>(Hb, D_MODEL, attn_in_w, D_MODEL, (float*)QKVb,
                                                  3 * D_MODEL, 3 * D_MODEL, D_MODEL, attn_in_b, 0,
                                                  1, 0);
    vtrans_kernel<<<dim3(8, 4, 16), 256, 0, stream>>>(QKVb, VTb);
    gemm_bb<<<dim3(2, 2, 16), 256, 0, stream>>>(
        QKVb, (long)SEQL * 3 * D_MODEL, HEAD_DIM, 3 * D_MODEL,
        QKVb + D_MODEL, (long)SEQL * 3 * D_MODEL, HEAD_DIM, 3 * D_MODEL,
        SBUF, 4L * SEQL * SEQL, (long)SEQL * SEQL, SEQL, HEAD_DIM, 0);
    softmax_kernel<<<BATCH * N_HEADS * SEQL, 256, 0, stream>>>(SBUF, Pb);
    gemm_bb<<<dim3(4, 2, 16), 256, 0, stream>>>(
        Pb, 4L * SEQL * SEQL, (long)SEQL * SEQL, SEQL,
        VTb, 4L * HEAD_DIM * SEQL, (long)HEAD_DIM * SEQL, SEQL,
        AOb, (long)SEQL * D_MODEL, HEAD_DIM, D_MODEL, SEQL, 1);
    gemm_bf16<<<dim3(16, 8, 1), 256, 0, stream>>>(AOb, D_MODEL, attn_out_w, D_MODEL, H, D_MODEL,
                                                  D_MODEL, D_MODEL, attn_out_b, 1, 0, 0);

    head_gemv1<<<dim3(256, 4), 256, 0, stream>>>(H, w1, b1, HM1);
    head_final<<<BATCH, 1024, 0, stream>>>(HM1, ln_g, ln_b, w2, b2, (float*)d_out);
}

// Round 5
// 1139.129 us; speedup vs baseline: 4.8444x; 1.1694x over previous
//
#include <hip/hip_runtime.h>
#include <hip/hip_bf16.h>
#include <math.h>

#define D_MODEL 2048
#define N_LAYERS 2
#define ED 4096
#define D_STATE 16
#define D_CONV 4
#define DT_RANK 128
#define N_HEADS 4
#define HEAD_DIM 512
#define BATCH 4
#define SEQL 256

typedef __bf16 bf16_t;
typedef bf16_t bf16x8 __attribute__((ext_vector_type(8)));
typedef bf16_t bf16x4 __attribute__((ext_vector_type(4)));
typedef float f32x4 __attribute__((ext_vector_type(4)));

// ---------------------------------------------------------------- utilities
__device__ __forceinline__ float warp_reduce_sum(float v) {
#pragma unroll
    for (int off = 1; off < 64; off <<= 1) v += __shfl_xor(v, off);
    return v;
}
__device__ __forceinline__ float warp_reduce_max(float v) {
#pragma unroll
    for (int off = 1; off < 64; off <<= 1) v = fmaxf(v, __shfl_xor(v, off));
    return v;
}

__device__ __forceinline__ void gload_lds16(const bf16_t* g, bf16_t* l) {
    __builtin_amdgcn_global_load_lds(
        (const __attribute__((address_space(1))) unsigned int*)g,
        (__attribute__((address_space(3))) unsigned int*)l, 16, 0, 0);
}

// ---------------------------------------------------------------- copy / convert
__global__ void copy_kernel(const float* __restrict__ src, float* __restrict__ dst, int n) {
    int i = blockIdx.x * blockDim.x + threadIdx.x;
    if (i < n) dst[i] = src[i];
}

__global__ void f2b_kernel(const float* __restrict__ src, bf16_t* __restrict__ dst, int n) {
    int i = blockIdx.x * blockDim.x + threadIdx.x;
    if (i < n) dst[i] = (bf16_t)src[i];
}

__global__ void dt_pack_kernel(const float* __restrict__ dbc, bf16_t* __restrict__ dt) {
    int i = blockIdx.x * blockDim.x + threadIdx.x;  // < 1024*128
    int row = i >> 7, col = i & 127;
    dt[i] = (bf16_t)dbc[row * (DT_RANK + 2 * D_STATE) + col];
}

__global__ void ksum_kernel(const float* __restrict__ part, float* __restrict__ out, int n,
                            int nz, long stride) {
    int i = blockIdx.x * blockDim.x + threadIdx.x;
    if (i >= n) return;
    float s = 0.f;
    for (int z = 0; z < nz; ++z) s += part[(long)z * stride + i];
    out[i] = s;
}

// ---------------------------------------------------------------- rmsnorm (bf16 out)
__global__ void rmsnorm_kernel(const float* __restrict__ x, const float* __restrict__ w,
                               bf16_t* __restrict__ o) {
    int row = blockIdx.x;
    int tid = threadIdx.x;  // 256
    const float* xr = x + (long)row * D_MODEL;
    float ss = 0.f;
    for (int i = tid; i < D_MODEL; i += 256) { float v = xr[i]; ss += v * v; }
    ss = warp_reduce_sum(ss);
    __shared__ float r[4];
    int wave = tid >> 6;
    if ((tid & 63) == 0) r[wave] = ss;
    __syncthreads();
    float tot = r[0] + r[1] + r[2] + r[3];
    float sc = rsqrtf(tot / (float)D_MODEL + 1e-5f);
    bf16_t* orow = o + (long)row * D_MODEL;
    for (int i = tid; i < D_MODEL; i += 256) orow[i] = (bf16_t)(xr[i] * sc * w[i]);
}

// ---------------------------------------------------------------- bf16 MFMA GEMM (fp32 B weights)
__global__ __launch_bounds__(256, 2) void gemm_bf16(
    const bf16_t* __restrict__ A, int lda, const float* __restrict__ B, int ldb,
    float* __restrict__ C, int ldc, int N, int K_len, const float* __restrict__ bias,
    int accumulate, int out_bf16, long partial_stride) {
    __shared__ bf16_t As[128 * 32];
    __shared__ bf16_t Bs[128 * 32];
    const int tid = threadIdx.x;
    const int lane = tid & 63;
    const int wave = tid >> 6;
    const int m0 = blockIdx.y * 128;
    const int n0 = blockIdx.x * 128;
    const int kbeg = blockIdx.z * K_len;

    const int cA = wave * 2;
    const bf16_t* gA0 = A + (long)(m0 + cA * 16 + (lane >> 2)) * lda + kbeg + (lane & 3) * 8;
    const bf16_t* gA1 = gA0 + 16L * lda;
    bf16_t* lA0 = &As[cA * 512];
    bf16_t* lA1 = &As[cA * 512 + 512];

    const int brow = tid >> 1;
    const int bcol = (tid & 1) * 16;
    const bool bvalid = (n0 + brow) < N;
    const float* gB = B + (long)(n0 + brow) * ldb + kbeg + bcol;
    bf16_t* lB = &Bs[brow * 32 + bcol];

    const int wr = wave >> 1, wc = wave & 1;
    const int fr = lane & 15, fq = lane >> 4;
    const bf16_t* aBase = &As[(wr * 64 + fr) * 32 + fq * 8];
    const bf16_t* bBase = &Bs[(wc * 64 + fr) * 32 + fq * 8];

    f32x4 acc[4][4] = {};

    for (int kk = 0; kk < K_len; kk += 32) {
        gload_lds16(gA0, lA0);
        gload_lds16(gA1, lA1);
        gA0 += 32;
        gA1 += 32;
        if (bvalid) {
            float4 v0 = *(const float4*)(gB);
            float4 v1 = *(const float4*)(gB + 4);
            float4 v2 = *(const float4*)(gB + 8);
            float4 v3 = *(const float4*)(gB + 12);
            gB += 32;
            bf16x8 p0, p1;
            p0[0] = (bf16_t)v0.x; p0[1] = (bf16_t)v0.y; p0[2] = (bf16_t)v0.z; p0[3] = (bf16_t)v0.w;
            p0[4] = (bf16_t)v1.x; p0[5] = (bf16_t)v1.y; p0[6] = (bf16_t)v1.z; p0[7] = (bf16_t)v1.w;
            p1[0] = (bf16_t)v2.x; p1[1] = (bf16_t)v2.y; p1[2] = (bf16_t)v2.z; p1[3] = (bf16_t)v2.w;
            p1[4] = (bf16_t)v3.x; p1[5] = (bf16_t)v3.y; p1[6] = (bf16_t)v3.z; p1[7] = (bf16_t)v3.w;
            *(bf16x8*)lB = p0;
            *((bf16x8*)lB + 1) = p1;
        }
        __syncthreads();
        bf16x8 af[4], bfr[4];
#pragma unroll
        for (int m = 0; m < 4; ++m) af[m] = *(const bf16x8*)(aBase + m * 512);
#pragma unroll
        for (int n = 0; n < 4; ++n) bfr[n] = *(const bf16x8*)(bBase + n * 512);
#pragma unroll
        for (int m = 0; m < 4; ++m)
#pragma unroll
            for (int n = 0; n < 4; ++n)
                acc[m][n] = __builtin_amdgcn_mfma_f32_16x16x32_bf16(af[m], bfr[n], acc[m][n], 0, 0, 0);
        __syncthreads();
    }

    float* Cz = C + ((gridDim.z > 1) ? (long)blockIdx.z * partial_stride : 0L);
#pragma unroll
    for (int m = 0; m < 4; ++m) {
        const int grow0 = m0 + wr * 64 + m * 16 + fq * 4;
#pragma unroll
        for (int n = 0; n < 4; ++n) {
            const int gcol = n0 + wc * 64 + n * 16 + fr;
            if (gcol >= N) continue;
            float bv = bias ? bias[gcol] : 0.f;
#pragma unroll
            for (int r = 0; r < 4; ++r) {
                long idx = (long)(grow0 + r) * ldc + gcol;
                float v = acc[m][n][r] + bv;
                if (out_bf16) {
                    ((bf16_t*)Cz)[idx] = (bf16_t)v;
                } else {
                    if (accumulate) v += Cz[idx];
                    Cz[idx] = v;
                }
            }
        }
    }
}

// ---------------------------------------------------------------- bf16xbf16 batched MFMA GEMM
__global__ __launch_bounds__(256, 2) void gemm_bb(
    const bf16_t* __restrict__ A, long aO, long aI, int lda,
    const bf16_t* __restrict__ B, long bO, long bI, int ldb,
    void* __restrict__ Cv, long cO, long cI, int ldc,
    int K_len, int out_bf16) {
    __shared__ bf16_t As[128 * 32];
    __shared__ bf16_t Bs[128 * 32];
    const int tid = threadIdx.x;
    const int lane = tid & 63;
    const int wave = tid >> 6;
    const int z = blockIdx.z, zb = z >> 2, zh = z & 3;
    const bf16_t* Az = A + (long)zb * aO + (long)zh * aI;
    const bf16_t* Bz = B + (long)zb * bO + (long)zh * bI;
    const int m0 = blockIdx.y * 128;
    const int n0 = blockIdx.x * 128;

    const int cA = wave * 2;
    const bf16_t* gA0 = Az + (long)(m0 + cA * 16 + (lane >> 2)) * lda + (lane & 3) * 8;
    const bf16_t* gA1 = gA0 + 16L * lda;
    const bf16_t* gB0 = Bz + (long)(n0 + cA * 16 + (lane >> 2)) * ldb + (lane & 3) * 8;
    const bf16_t* gB1 = gB0 + 16L * ldb;
    bf16_t* lA0 = &As[cA * 512];
    bf16_t* lA1 = lA0 + 512;
    bf16_t* lB0 = &Bs[cA * 512];
    bf16_t* lB1 = lB0 + 512;

    const int wr = wave >> 1, wc = wave & 1;
    const int fr = lane & 15, fq = lane >> 4;
    const bf16_t* aBase = &As[(wr * 64 + fr) * 32 + fq * 8];
    const bf16_t* bBase = &Bs[(wc * 64 + fr) * 32 + fq * 8];

    f32x4 acc[4][4] = {};

    for (int kk = 0; kk < K_len; kk += 32) {
        gload_lds16(gA0, lA0);
        gload_lds16(gA1, lA1);
        gload_lds16(gB0, lB0);
        gload_lds16(gB1, lB1);
        gA0 += 32; gA1 += 32; gB0 += 32; gB1 += 32;
        __syncthreads();
        bf16x8 af[4], bfr[4];
#pragma unroll
        for (int m = 0; m < 4; ++m) af[m] = *(const bf16x8*)(aBase + m * 512);
#pragma unroll
        for (int n = 0; n < 4; ++n) bfr[n] = *(const bf16x8*)(bBase + n * 512);
#pragma unroll
        for (int m = 0; m < 4; ++m)
#pragma unroll
            for (int n = 0; n < 4; ++n)
                acc[m][n] = __builtin_amdgcn_mfma_f32_16x16x32_bf16(af[m], bfr[n], acc[m][n], 0, 0, 0);
        __syncthreads();
    }

#pragma unroll
    for (int m = 0; m < 4; ++m) {
        const int grow0 = m0 + wr * 64 + m * 16 + fq * 4;
#pragma unroll
        for (int n = 0; n < 4; ++n) {
            const int gcol = n0 + wc * 64 + n * 16 + fr;
#pragma unroll
            for (int r = 0; r < 4; ++r) {
                long idx = (long)(grow0 + r) * ldc + gcol;
                if (out_bf16) {
                    bf16_t* Cb = (bf16_t*)Cv + (long)zb * cO + (long)zh * cI;
                    Cb[idx] = (bf16_t)acc[m][n][r];
                } else {
                    float* Cf = (float*)Cv + (long)zb * cO + (long)zh * cI;
                    Cf[idx] = acc[m][n][r];
                }
            }
        }
    }
}

// ---------------------------------------------------------------- V transpose (attention)
__global__ void vtrans_kernel(const bf16_t* __restrict__ qkvb, bf16_t* __restrict__ vt) {
    int z = blockIdx.z;  // b*4+h
    int b = z >> 2, h = z & 3;
    int d0 = blockIdx.x * 64, k0 = blockIdx.y * 64;
    __shared__ bf16_t tile[64][72];
    int t = threadIdx.x;  // 256
    int r = t >> 2;
    int c4 = (t & 3) * 16;
    const bf16_t* src = qkvb + ((long)(b * SEQL + k0 + r)) * (3 * D_MODEL) + 2 * D_MODEL +
                        h * HEAD_DIM + d0 + c4;
    bf16x8 v0 = *(const bf16x8*)src;
    bf16x8 v1 = *(const bf16x8*)(src + 8);
#pragma unroll
    for (int j = 0; j < 8; ++j) tile[r][c4 + j] = v0[j];
#pragma unroll
    for (int j = 0; j < 8; ++j) tile[r][c4 + 8 + j] = v1[j];
    __syncthreads();
    int dd = t >> 2, kc = (t & 3) * 16;
    bf16_t* dst = vt + (long)z * (HEAD_DIM * SEQL) + (long)(d0 + dd) * SEQL + k0 + kc;
    bf16x8 o0, o1;
#pragma unroll
    for (int j = 0; j < 8; ++j) o0[j] = tile[kc + j][dd];
#pragma unroll
    for (int j = 0; j < 8; ++j) o1[j] = tile[kc + 8 + j][dd];
    *(bf16x8*)dst = o0;
    *(bf16x8*)(dst + 8) = o1;
}

// ---------------------------------------------------------------- softmax rows of S
__global__ void softmax_kernel(const float* __restrict__ S, bf16_t* __restrict__ P) {
    long row = blockIdx.x;  // 4096 = (b,h,q)
    int tid = threadIdx.x;  // 256
    float s = S[row * SEQL + tid] * 0.044194173824159216f;  // 1/sqrt(512)
    __shared__ float red[4];
    float m = warp_reduce_max(s);
    if ((tid & 63) == 0) red[tid >> 6] = m;
    __syncthreads();
    float gm = fmaxf(fmaxf(red[0], red[1]), fmaxf(red[2], red[3]));
    __syncthreads();
    float p = __expf(s - gm);
    float su = warp_reduce_sum(p);
    if ((tid & 63) == 0) red[tid >> 6] = su;
    __syncthreads();
    float gs = red[0] + red[1] + red[2] + red[3];
    P[row * SEQL + tid] = (bf16_t)(p / gs);
}

// ---------------------------------------------------------------- conv + silu + transpose
// reads XZb [B*L][2ED]; writes xT [B][ED][L] (bf16), XCb [B*L][ED] (bf16), zT [B][ED][L] (bf16)
__global__ void conv_tr_kernel(const bf16_t* __restrict__ xzb, const float* __restrict__ cw,
                               const float* __restrict__ cb, bf16_t* __restrict__ xT,
                               bf16_t* __restrict__ xcb, bf16_t* __restrict__ zT) {
    __shared__ bf16_t xin[68][64];
    __shared__ bf16_t outt[64][72];  // [e_local][l_local]
    const int e0 = blockIdx.x * 64, l0 = blockIdx.y * 64, b = blockIdx.z;
    const int t = threadIdx.x;
    const int r = t >> 4;            // 0..15
    const int c = (t & 15) * 4;      // 0..60

    // load xin rows l0-3 .. l0+63 (67 rows)
#pragma unroll
    for (int i = 0; i < 5; ++i) {
        int m = r + i * 16;
        if (m < 67) {
            int l = l0 - 3 + m;
            bf16x4 v;
            if (l >= 0)
                v = *(const bf16x4*)(xzb + ((long)(b * SEQL + l)) * (2 * ED) + e0 + c);
            else {
                v[0] = (bf16_t)0.f; v[1] = (bf16_t)0.f; v[2] = (bf16_t)0.f; v[3] = (bf16_t)0.f;
            }
            *(bf16x4*)&xin[m][c] = v;
        }
    }
    __syncthreads();

    // compute conv+silu: thread owns column e_l, 16 rows
    {
        const int e_l = t & 63;
        const int lbase = (t >> 6) * 16;
        const float4 wv = *(const float4*)(cw + (long)(e0 + e_l) * 4);
        const float bias = cb[e0 + e_l];
#pragma unroll
        for (int k = 0; k < 16; ++k) {
            int l = lbase + k;
            float acc = bias + wv.x * (float)xin[l][e_l] + wv.y * (float)xin[l + 1][e_l] +
                        wv.z * (float)xin[l + 2][e_l] + wv.w * (float)xin[l + 3][e_l];
            float s = acc / (1.f + __expf(-acc));
            outt[e_l][l] = (bf16_t)s;
        }
    }
    __syncthreads();

    // write xT (transposed layout: rows = e)
    {
        int er = t >> 2, lc = (t & 3) * 16;
        bf16x8 a = *(bf16x8*)&outt[er][lc];
        bf16x8 bb8 = *(bf16x8*)&outt[er][lc + 8];
        bf16_t* dst = xT + ((long)b * ED + e0 + er) * SEQL + l0 + lc;
        *(bf16x8*)dst = a;
        *(bf16x8*)(dst + 8) = bb8;
    }
    // write XCb (normal layout: rows = l)
    {
        int lr = t >> 2, ec = (t & 3) * 16;
        bf16_t tmp[16];
#pragma unroll
        for (int j = 0; j < 16; ++j) tmp[j] = outt[ec + j][lr];
        bf16_t* dst = xcb + ((long)(b * SEQL + l0 + lr)) * ED + e0 + ec;
        *(bf16x8*)dst = *(bf16x8*)&tmp[0];
        *(bf16x8*)(dst + 8) = *(bf16x8*)&tmp[8];
    }
    __syncthreads();

    // z tile: load rows l0..l0+63 of z half, transpose out
#pragma unroll
    for (int i = 0; i < 4; ++i) {
        int m = r + i * 16;
        bf16x4 v = *(const bf16x4*)(xzb + ((long)(b * SEQL + l0 + m)) * (2 * ED) + ED + e0 + c);
        *(bf16x4*)&xin[m][c] = v;
    }
    __syncthreads();
    {
        int er = t >> 2, lc = (t & 3) * 16;
        bf16_t tz[16];
#pragma unroll
        for (int j = 0; j < 16; ++j) tz[j] = xin[lc + j][er];
        bf16_t* dst = zT + ((long)b * ED + e0 + er) * SEQL + l0 + lc;
        *(bf16x8*)dst = *(bf16x8*)&tz[0];
        *(bf16x8*)(dst + 8) = *(bf16x8*)&tz[8];
    }
}

// ---------------------------------------------------------------- softplus + transpose
// reads DELTA [B*L][ED] (+dt_b), writes dT [B][ED][L] f32
__global__ void softplus_tr_kernel(const float* __restrict__ delta, const float* __restrict__ dt_b,
                                   float* __restrict__ dT) {
    __shared__ float tile[64][65];
    const int e0 = blockIdx.x * 64, l0 = blockIdx.y * 64, b = blockIdx.z;
    const int t = threadIdx.x;
    const int r = t >> 4, c = (t & 15) * 4;
#pragma unroll
    for (int i = 0; i < 4; ++i) {
        int l = r + i * 16;
        float4 v = *(const float4*)(delta + ((long)(b * SEQL + l0 + l)) * ED + e0 + c);
        float4 bb = *(const float4*)(dt_b + e0 + c);
        float u0 = v.x + bb.x, u1 = v.y + bb.y, u2 = v.z + bb.z, u3 = v.w + bb.w;
        tile[l][c] = (u0 > 20.f) ? u0 : log1pf(__expf(u0));
        tile[l][c + 1] = (u1 > 20.f) ? u1 : log1pf(__expf(u1));
        tile[l][c + 2] = (u2 > 20.f) ? u2 : log1pf(__expf(u2));
        tile[l][c + 3] = (u3 > 20.f) ? u3 : log1pf(__expf(u3));
    }
    __syncthreads();
#pragma unroll
    for (int i = 0; i < 4; ++i) {
        int ee = r + i * 16;
        float4 w;
        w.x = tile[c][ee];
        w.y = tile[c + 1][ee];
        w.z = tile[c + 2][ee];
        w.w = tile[c + 3][ee];
        *(float4*)(dT + ((long)b * ED + e0 + ee) * SEQL + l0 + c) = w;
    }
}

// ---------------------------------------------------------------- chunk-parallel selective scan
// lane owns (e, chunk): 16 chunks of 16 steps. block 256 = 16 e x 16 chunks.
// grid = (ED/16, B)
__global__ __launch_bounds__(256) void scan_chunk_kernel(
    const float* __restrict__ dT, const bf16_t* __restrict__ xT, const bf16_t* __restrict__ zT,
    const float* __restrict__ dbc, const float* __restrict__ A_log, const float* __restrict__ Dp,
    bf16_t* __restrict__ yT) {
    const int t = threadIdx.x;
    const int chunk = t & 15;
    const int el = t >> 4;
    const int b = blockIdx.y;
    const int e = blockIdx.x * 16 + el;
    const int l0 = chunk * 16;

    float Ar[16];
    {
        const float* ap = A_log + (long)e * D_STATE;
#pragma unroll
        for (int n = 0; n < 16; n += 4) {
            float4 v = *(const float4*)(ap + n);
            Ar[n] = -__expf(v.x);
            Ar[n + 1] = -__expf(v.y);
            Ar[n + 2] = -__expf(v.z);
            Ar[n + 3] = -__expf(v.w);
        }
    }
    float d[16];
    {
        const float* dp = dT + ((long)b * ED + e) * SEQL + l0;
#pragma unroll
        for (int j = 0; j < 16; j += 4) *(float4*)&d[j] = *(const float4*)(dp + j);
    }
    float xf[16];
    {
        const bf16_t* xp = xT + ((long)b * ED + e) * SEQL + l0;
        bf16x8 x0 = *(const bf16x8*)xp;
        bf16x8 x1 = *(const bf16x8*)(xp + 8);
#pragma unroll
        for (int j = 0; j < 8; ++j) {
            xf[j] = (float)x0[j];
            xf[8 + j] = (float)x1[j];
        }
    }
    const float* bcbase = dbc + ((long)b * SEQL) * (DT_RANK + 2 * D_STATE) + DT_RANK;

    float P[16], S[16];
#pragma unroll
    for (int n = 0; n < 16; ++n) {
        P[n] = 1.f;
        S[n] = 0.f;
    }

    // pass A: per-chunk summary from h=0
#pragma unroll
    for (int j = 0; j < 16; ++j) {
        const float* br = bcbase + (long)(l0 + j) * (DT_RANK + 2 * D_STATE);
        float Bv[16];
#pragma unroll
        for (int n = 0; n < 16; n += 4) *(float4*)&Bv[n] = *(const float4*)(br + n);
        float dx = d[j] * xf[j];
#pragma unroll
        for (int n = 0; n < 16; ++n) {
            float dA = __expf(d[j] * Ar[n]);
            S[n] = dA * S[n] + dx * Bv[n];
            P[n] *= dA;
        }
    }

    // combine: inclusive scan over 16 chunk-lanes
#pragma unroll
    for (int off = 1; off < 16; off <<= 1) {
        float Pp[16], Sp[16];
#pragma unroll
        for (int n = 0; n < 16; ++n) {
            Pp[n] = __shfl_up(P[n], off, 16);
            Sp[n] = __shfl_up(S[n], off, 16);
        }
        if (chunk >= off) {
#pragma unroll
            for (int n = 0; n < 16; ++n) {
                S[n] = P[n] * Sp[n] + S[n];
                P[n] *= Pp[n];
            }
        }
    }

    // exclusive: h_init[chunk] = inclusive_S[chunk-1]
    float h[16];
#pragma unroll
    for (int n = 0; n < 16; ++n) {
        float hs = __shfl_up(S[n], 1, 16);
        h[n] = (chunk == 0) ? 0.f : hs;
    }

    const float dpe = Dp[e];
    float zf[16];
    {
        const bf16_t* zp = zT + ((long)b * ED + e) * SEQL + l0;
        bf16x8 z0 = *(const bf16x8*)zp;
        bf16x8 z1 = *(const bf16x8*)(zp + 8);
#pragma unroll
        for (int j = 0; j < 8; ++j) {
            zf[j] = (float)z0[j];
            zf[8 + j] = (float)z1[j];
        }
    }

    bf16_t yv[16];
    // pass C: replay with true h_init
#pragma unroll
    for (int j = 0; j < 16; ++j) {
        const float* br = bcbase + (long)(l0 + j) * (DT_RANK + 2 * D_STATE);
        float Bv[16], Cv[16];
#pragma unroll
        for (int n = 0; n < 16; n += 4) *(float4*)&Bv[n] = *(const float4*)(br + n);
#pragma unroll
        for (int n = 0; n < 16; n += 4) *(float4*)&Cv[n] = *(const float4*)(br + D_STATE + n);
        float dx = d[j] * xf[j];
        float y = 0.f;
#pragma unroll
        for (int n = 0; n < 16; ++n) {
            float dA = __expf(d[j] * Ar[n]);
            h[n] = dA * h[n] + dx * Bv[n];
            y += h[n] * Cv[n];
        }
        y += xf[j] * dpe;
        float z = zf[j];
        y *= z / (1.f + __expf(-z));
        yv[j] = (bf16_t)y;
    }
    bf16_t* yp = yT + ((long)b * ED + e) * SEQL + l0;
    *(bf16x8*)yp = *(bf16x8*)&yv[0];
    *(bf16x8*)(yp + 8) = *(bf16x8*)&yv[8];
}

// ---------------------------------------------------------------- yT [B][ED][L] -> Y [B*L][ED]
__global__ void ytr_kernel(const bf16_t* __restrict__ yT, bf16_t* __restrict__ Y) {
    __shared__ bf16_t tl[64][72];
    const int e0 = blockIdx.x * 64, l0 = blockIdx.y * 64, b = blockIdx.z;
    const int t = threadIdx.x;
    {
        int er = t >> 2, lc = (t & 3) * 16;
        const bf16_t* src = yT + ((long)b * ED + e0 + er) * SEQL + l0 + lc;
        bf16x8 a = *(const bf16x8*)src;
        bf16x8 bb8 = *(const bf16x8*)(src + 8);
        *(bf16x8*)&tl[er][lc] = a;
        *(bf16x8*)&tl[er][lc + 8] = bb8;
    }
    __syncthreads();
    {
        int lr = t >> 2, ec = (t & 3) * 16;
        bf16_t tmp[16];
#pragma unroll
        for (int j = 0; j < 16; ++j) tmp[j] = tl[ec + j][lr];
        bf16_t* dst = Y + ((long)(b * SEQL + l0 + lr)) * ED + e0 + ec;
        *(bf16x8*)dst = *(bf16x8*)&tmp[0];
        *(bf16x8*)(dst + 8) = *(bf16x8*)&tmp[8];
    }
}

// ---------------------------------------------------------------- head GEMV1
__global__ void head_gemv1(const float* __restrict__ H, const float* __restrict__ w1,
                           const float* __restrict__ b1, float* __restrict__ hm1) {
    int b = blockIdx.y;
    int wave = threadIdx.x >> 6, lane = threadIdx.x & 63;
    int n = blockIdx.x * 4 + wave;
    const float* last = H + ((long)(b * SEQL + SEQL - 1)) * D_MODEL;
    const float* wr = w1 + (long)n * D_MODEL;
    float s = 0.f;
    for (int j = lane * 4; j < D_MODEL; j += 256) {
        float4 a = *(const float4*)(last + j);
        float4 w = *(const float4*)(wr + j);
        s += a.x * w.x + a.y * w.y + a.z * w.z + a.w * w.w;
    }
    s = warp_reduce_sum(s);
    if (lane == 0) hm1[b * 1024 + n] = s + b1[n];
}

// ---------------------------------------------------------------- head final
__global__ void head_final(const float* __restrict__ hm1, const float* __restrict__ ln_g,
                           const float* __restrict__ ln_b, const float* __restrict__ w2,
                           const float* __restrict__ b2, float* __restrict__ out) {
    int b = blockIdx.x;
    int tid = threadIdx.x;  // 1024
    __shared__ float hm[1024];
    __shared__ float r1[16], r2[16];
    __shared__ float stats[2];
    __shared__ float outs[64];

    float v = hm1[b * 1024 + tid];
    float s1 = warp_reduce_sum(v);
    float s2 = warp_reduce_sum(v * v);
    int wave = tid >> 6;
    if ((tid & 63) == 0) { r1[wave] = s1; r2[wave] = s2; }
    __syncthreads();
    if (tid == 0) {
        float t1 = 0.f, t2 = 0.f;
        for (int w = 0; w < 16; ++w) { t1 += r1[w]; t2 += r2[w]; }
        float mean = t1 / 1024.f;
        stats[0] = mean;
        stats[1] = rsqrtf(t2 / 1024.f - mean * mean + 1e-5f);
    }
    __syncthreads();
    float x = (v - stats[0]) * stats[1] * ln_g[tid] + ln_b[tid];
    x = (x > 0.f) ? x : (__expf(x) - 1.f);
    hm[tid] = x;
    __syncthreads();

    int o = tid >> 4, kk = tid & 15;
    float a = 0.f;
    const float* w2r = w2 + (long)o * 1024;
    for (int j = kk; j < 1024; j += 16) a += hm[j] * w2r[j];
#pragma unroll
    for (int off = 1; off < 16; off <<= 1) a += __shfl_xor(a, off);
    if (kk == 0) outs[o] = a + b2[o];
    __syncthreads();
    if (tid < 64) {
        float vv = outs[tid];
        float ss = warp_reduce_sum(vv * vv);
        out[b * 64 + tid] = vv / fmaxf(sqrtf(ss), 1e-12f);
    }
}

// ---------------------------------------------------------------- launch
extern "C" void kernel_launch(void* const* d_in, const int* in_sizes, int n_in,
                              void* d_out, int out_size, void* d_ws, size_t ws_size,
                              hipStream_t stream) {
    const float* x = (const float*)d_in[0];
    const float* norm_w = (const float*)d_in[1];
    const float* in_proj_w = (const float*)d_in[2];
    const float* conv_w = (const float*)d_in[3];
    const float* conv_b = (const float*)d_in[4];
    const float* x_proj_w = (const float*)d_in[5];
    const float* dt_proj_w = (const float*)d_in[6];
    const float* dt_proj_b = (const float*)d_in[7];
    const float* A_log = (const float*)d_in[8];
    const float* D_param = (const float*)d_in[9];
    const float* out_proj_w = (const float*)d_in[10];
    const float* attn_in_w = (const float*)d_in[11];
    const float* attn_in_b = (const float*)d_in[12];
    const float* attn_out_w = (const float*)d_in[13];
    const float* attn_out_b = (const float*)d_in[14];
    const float* w1 = (const float*)d_in[15];
    const float* b1 = (const float*)d_in[16];
    const float* ln_g = (const float*)d_in[17];
    const float* ln_b = (const float*)d_in[18];
    const float* w2 = (const float*)d_in[19];
    const float* b2 = (const float*)d_in[20];

    float* ws = (float*)d_ws;
    size_t o = 0;
    float* H = ws + o;      o += 2097152;       // (B,L,D) fp32
    float* SCR = ws + o;    o += 6291456;       // XZb/dT/yT (mamba) | QKV etc (attn)
    float* DELTA = ws + o;  o += 4194304;       // (B,L,ED) fp32
    float* DBC = ws + o;    o += 163840;        // (B,L,160) fp32
    float* XPART = ws + o;  o += 1310720;       // 8 x (1024,160) split-K partials
    bf16_t* XNb = (bf16_t*)(ws + o);  o += 1048576;  // (B,L,D) bf16
    bf16_t* XCb = (bf16_t*)(ws + o);  o += 2097152;  // (B,L,ED) bf16
    bf16_t* DTb = (bf16_t*)(ws + o);  o += 65536;    // (1024,128) bf16
    bf16_t* Yb = (bf16_t*)(ws + o);   o += 2097152;  // (B,L,ED) bf16
    bf16_t* Hb = (bf16_t*)(ws + o);   o += 1048576;  // (B,L,D) bf16
    bf16_t* AOb = (bf16_t*)(ws + o);  o += 1048576;  // (B,L,D) bf16
    float* HM1 = ws + o;    o += 4096;          // (B,1024) fp32
    bf16_t* XT = (bf16_t*)(ws + o);   o += 2097152;  // [B][ED][L] bf16
    bf16_t* ZT = (bf16_t*)(ws + o);   o += 2097152;  // [B][ED][L] bf16

    bf16_t* XZb = (bf16_t*)SCR;                       // [B*L][2ED] bf16 (dead after conv_tr)
    float* DTT = SCR;                                 // [B][ED][L] f32 (aliases XZb; written after)
    bf16_t* YTT = (bf16_t*)(SCR + 4194304);           // [B][ED][L] bf16

    bf16_t* QKVb = (bf16_t*)SCR;                      // attention phase
    float* SBUF = SCR + 3145728;
    bf16_t* Pb = (bf16_t*)(SCR + 3145728 + 1048576);
    bf16_t* VTb = (bf16_t*)(SCR + 3145728 + 1048576 + 524288);

    const int M = BATCH * SEQL;  // 1024
    const long S_H = (long)M * D_MODEL;

    copy_kernel<<<(S_H + 255) / 256, 256, 0, stream>>>(x, H, (int)S_H);

    for (int i = 0; i < N_LAYERS; ++i) {
        rmsnorm_kernel<<<M, 256, 0, stream>>>(H, norm_w + (long)i * D_MODEL, XNb);
        gemm_bf16<<<dim3(64, 8, 1), 256, 0, stream>>>(
            XNb, D_MODEL, in_proj_w + (long)i * 2 * ED * D_MODEL, D_MODEL, (float*)XZb, 2 * ED,
            2 * ED, D_MODEL, nullptr, 0, 1, 0);
        conv_tr_kernel<<<dim3(64, 4, 4), 256, 0, stream>>>(
            XZb, conv_w + (long)i * ED * D_CONV, conv_b + (long)i * ED, XT, XCb, ZT);
        gemm_bf16<<<dim3(2, 8, 8), 256, 0, stream>>>(
            XCb, ED, x_proj_w + (long)i * (DT_RANK + 2 * D_STATE) * ED, ED, XPART,
            DT_RANK + 2 * D_STATE, DT_RANK + 2 * D_STATE, ED / 8, nullptr, 0, 0,
            (long)M * (DT_RANK + 2 * D_STATE));
        ksum_kernel<<<640, 256, 0, stream>>>(XPART, DBC, M * (DT_RANK + 2 * D_STATE), 8,
                                             (long)M * (DT_RANK + 2 * D_STATE));
        dt_pack_kernel<<<512, 256, 0, stream>>>(DBC, DTb);
        gemm_bf16<<<dim3(32, 8, 1), 256, 0, stream>>>(
            DTb, DT_RANK, dt_proj_w + (long)i * ED * DT_RANK, DT_RANK, DELTA, ED, ED, DT_RANK,
            nullptr, 0, 0, 0);
        softplus_tr_kernel<<<dim3(64, 4, 4), 256, 0, stream>>>(DELTA, dt_proj_b + (long)i * ED,
                                                               DTT);
        scan_chunk_kernel<<<dim3(ED / 16, BATCH), 256, 0, stream>>>(
            DTT, XT, ZT, DBC, A_log + (long)i * ED * D_STATE, D_param + (long)i * ED, YTT);
        ytr_kernel<<<dim3(64, 4, 4), 256, 0, stream>>>(YTT, Yb);
        gemm_bf16<<<dim3(16, 8, 1), 256, 0, stream>>>(
            Yb, ED, out_proj_w + (long)i * D_MODEL * ED, ED, H, D_MODEL, D_MODEL, ED, nullptr, 1,
            0, 0);
    }

    f2b_kernel<<<(int)((S_H + 255) / 256), 256, 0, stream>>>(H, Hb, (int)S_H);
    gemm_bf16<<<dim3(48, 8, 1), 256, 0, stream>>>(Hb, D_MODEL, attn_in_w, D_MODEL, (float*)QKVb,
                                                  3 * D_MODEL, 3 * D_MODEL, D_MODEL, attn_in_b, 0,
                                                  1, 0);
    vtrans_kernel<<<dim3(8, 4, 16), 256, 0, stream>>>(QKVb, VTb);
    gemm_bb<<<dim3(2, 2, 16), 256, 0, stream>>>(
        QKVb, (long)SEQL * 3 * D_MODEL, HEAD_DIM, 3 * D_MODEL,
        QKVb + D_MODEL, (long)SEQL * 3 * D_MODEL, HEAD_DIM, 3 * D_MODEL,
        SBUF, 4L * SEQL * SEQL, (long)SEQL * SEQL, SEQL, HEAD_DIM, 0);
    softmax_kernel<<<BATCH * N_HEADS * SEQL, 256, 0, stream>>>(SBUF, Pb);
    gemm_bb<<<dim3(4, 2, 16), 256, 0, stream>>>(
        Pb, 4L * SEQL * SEQL, (long)SEQL * SEQL, SEQL,
        VTb, 4L * HEAD_DIM * SEQL, (long)HEAD_DIM * SEQL, SEQL,
        AOb, (long)SEQL * D_MODEL, HEAD_DIM, D_MODEL, SEQL, 1);
    gemm_bf16<<<dim3(16, 8, 1), 256, 0, stream>>>(AOb, D_MODEL, attn_out_w, D_MODEL, H, D_MODEL,
                                                  D_MODEL, D_MODEL, attn_out_b, 1, 0, 0);

    head_gemv1<<<dim3(256, 4), 256, 0, stream>>>(H, w1, b1, HM1);
    head_final<<<BATCH, 1024, 0, stream>>>(HM1, ln_g, ln_b, w2, b2, (float*)d_out);
}

// Round 6
// 881.096 us; speedup vs baseline: 6.2630x; 1.2929x over previous
//
#include <hip/hip_runtime.h>
#include <hip/hip_bf16.h>
#include <math.h>

#define D_MODEL 2048
#define N_LAYERS 2
#define ED 4096
#define D_STATE 16
#define D_CONV 4
#define DT_RANK 128
#define N_HEADS 4
#define HEAD_DIM 512
#define BATCH 4
#define SEQL 256

typedef __bf16 bf16_t;
typedef bf16_t bf16x8 __attribute__((ext_vector_type(8)));
typedef bf16_t bf16x4 __attribute__((ext_vector_type(4)));
typedef float f32x4 __attribute__((ext_vector_type(4)));

// ---------------------------------------------------------------- utilities
__device__ __forceinline__ float warp_reduce_sum(float v) {
#pragma unroll
    for (int off = 1; off < 64; off <<= 1) v += __shfl_xor(v, off);
    return v;
}
__device__ __forceinline__ float warp_reduce_max(float v) {
#pragma unroll
    for (int off = 1; off < 64; off <<= 1) v = fmaxf(v, __shfl_xor(v, off));
    return v;
}

__device__ __forceinline__ void gload_lds16(const bf16_t* g, bf16_t* l) {
    __builtin_amdgcn_global_load_lds(
        (const __attribute__((address_space(1))) unsigned int*)g,
        (__attribute__((address_space(3))) unsigned int*)l, 16, 0, 0);
}

// ---------------------------------------------------------------- copy / convert
__global__ void copy_kernel(const float* __restrict__ src, float* __restrict__ dst, int n) {
    int i = blockIdx.x * blockDim.x + threadIdx.x;
    if (i < n) dst[i] = src[i];
}

__global__ void f2b_kernel(const float* __restrict__ src, bf16_t* __restrict__ dst, int n) {
    int i = blockIdx.x * blockDim.x + threadIdx.x;
    if (i < n) dst[i] = (bf16_t)src[i];
}

__global__ void dt_pack_kernel(const float* __restrict__ dbc, bf16_t* __restrict__ dt) {
    int i = blockIdx.x * blockDim.x + threadIdx.x;  // < 1024*128
    int row = i >> 7, col = i & 127;
    dt[i] = (bf16_t)dbc[row * (DT_RANK + 2 * D_STATE) + col];
}

__global__ void ksum_kernel(const float* __restrict__ part, float* __restrict__ out, int n,
                            int nz, long stride) {
    int i = blockIdx.x * blockDim.x + threadIdx.x;
    if (i >= n) return;
    float s = 0.f;
    for (int z = 0; z < nz; ++z) s += part[(long)z * stride + i];
    out[i] = s;
}

// sum split-K partials and ADD into out (+ optional bias, indexed i & bmask)
__global__ void ksum_add_kernel(const float* __restrict__ part, float* __restrict__ out, int n,
                                int nz, long stride, const float* __restrict__ bias, int bmask) {
    int i = blockIdx.x * blockDim.x + threadIdx.x;
    if (i >= n) return;
    float s = out[i];
    for (int z = 0; z < nz; ++z) s += part[(long)z * stride + i];
    if (bias) s += bias[i & bmask];
    out[i] = s;
}

// ---------------------------------------------------------------- rmsnorm (bf16 out)
__global__ void rmsnorm_kernel(const float* __restrict__ x, const float* __restrict__ w,
                               bf16_t* __restrict__ o) {
    int row = blockIdx.x;
    int tid = threadIdx.x;  // 256
    const float* xr = x + (long)row * D_MODEL;
    float ss = 0.f;
    for (int i = tid; i < D_MODEL; i += 256) { float v = xr[i]; ss += v * v; }
    ss = warp_reduce_sum(ss);
    __shared__ float r[4];
    int wave = tid >> 6;
    if ((tid & 63) == 0) r[wave] = ss;
    __syncthreads();
    float tot = r[0] + r[1] + r[2] + r[3];
    float sc = rsqrtf(tot / (float)D_MODEL + 1e-5f);
    bf16_t* orow = o + (long)row * D_MODEL;
    for (int i = tid; i < D_MODEL; i += 256) orow[i] = (bf16_t)(xr[i] * sc * w[i]);
}

// ---------------------------------------------------------------- bf16 MFMA GEMM (fp32 B weights)
__global__ __launch_bounds__(256, 2) void gemm_bf16(
    const bf16_t* __restrict__ A, int lda, const float* __restrict__ B, int ldb,
    float* __restrict__ C, int ldc, int N, int K_len, const float* __restrict__ bias,
    int accumulate, int out_bf16, long partial_stride) {
    __shared__ bf16_t As[128 * 32];
    __shared__ bf16_t Bs[128 * 32];
    const int tid = threadIdx.x;
    const int lane = tid & 63;
    const int wave = tid >> 6;
    const int m0 = blockIdx.y * 128;
    const int n0 = blockIdx.x * 128;
    const int kbeg = blockIdx.z * K_len;

    const int cA = wave * 2;
    const bf16_t* gA0 = A + (long)(m0 + cA * 16 + (lane >> 2)) * lda + kbeg + (lane & 3) * 8;
    const bf16_t* gA1 = gA0 + 16L * lda;
    bf16_t* lA0 = &As[cA * 512];
    bf16_t* lA1 = &As[cA * 512 + 512];

    const int brow = tid >> 1;
    const int bcol = (tid & 1) * 16;
    const bool bvalid = (n0 + brow) < N;
    const float* gB = B + (long)(n0 + brow) * ldb + kbeg + bcol;
    bf16_t* lB = &Bs[brow * 32 + bcol];

    const int wr = wave >> 1, wc = wave & 1;
    const int fr = lane & 15, fq = lane >> 4;
    const bf16_t* aBase = &As[(wr * 64 + fr) * 32 + fq * 8];
    const bf16_t* bBase = &Bs[(wc * 64 + fr) * 32 + fq * 8];

    f32x4 acc[4][4] = {};

    for (int kk = 0; kk < K_len; kk += 32) {
        gload_lds16(gA0, lA0);
        gload_lds16(gA1, lA1);
        gA0 += 32;
        gA1 += 32;
        if (bvalid) {
            float4 v0 = *(const float4*)(gB);
            float4 v1 = *(const float4*)(gB + 4);
            float4 v2 = *(const float4*)(gB + 8);
            float4 v3 = *(const float4*)(gB + 12);
            gB += 32;
            bf16x8 p0, p1;
            p0[0] = (bf16_t)v0.x; p0[1] = (bf16_t)v0.y; p0[2] = (bf16_t)v0.z; p0[3] = (bf16_t)v0.w;
            p0[4] = (bf16_t)v1.x; p0[5] = (bf16_t)v1.y; p0[6] = (bf16_t)v1.z; p0[7] = (bf16_t)v1.w;
            p1[0] = (bf16_t)v2.x; p1[1] = (bf16_t)v2.y; p1[2] = (bf16_t)v2.z; p1[3] = (bf16_t)v2.w;
            p1[4] = (bf16_t)v3.x; p1[5] = (bf16_t)v3.y; p1[6] = (bf16_t)v3.z; p1[7] = (bf16_t)v3.w;
            *(bf16x8*)lB = p0;
            *((bf16x8*)lB + 1) = p1;
        }
        __syncthreads();
        bf16x8 af[4], bfr[4];
#pragma unroll
        for (int m = 0; m < 4; ++m) af[m] = *(const bf16x8*)(aBase + m * 512);
#pragma unroll
        for (int n = 0; n < 4; ++n) bfr[n] = *(const bf16x8*)(bBase + n * 512);
#pragma unroll
        for (int m = 0; m < 4; ++m)
#pragma unroll
            for (int n = 0; n < 4; ++n)
                acc[m][n] = __builtin_amdgcn_mfma_f32_16x16x32_bf16(af[m], bfr[n], acc[m][n], 0, 0, 0);
        __syncthreads();
    }

    float* Cz = C + ((gridDim.z > 1) ? (long)blockIdx.z * partial_stride : 0L);
#pragma unroll
    for (int m = 0; m < 4; ++m) {
        const int grow0 = m0 + wr * 64 + m * 16 + fq * 4;
#pragma unroll
        for (int n = 0; n < 4; ++n) {
            const int gcol = n0 + wc * 64 + n * 16 + fr;
            if (gcol >= N) continue;
            float bv = bias ? bias[gcol] : 0.f;
#pragma unroll
            for (int r = 0; r < 4; ++r) {
                long idx = (long)(grow0 + r) * ldc + gcol;
                float v = acc[m][n][r] + bv;
                if (out_bf16) {
                    ((bf16_t*)Cz)[idx] = (bf16_t)v;
                } else {
                    if (accumulate) v += Cz[idx];
                    Cz[idx] = v;
                }
            }
        }
    }
}

// ---------------------------------------------------------------- bf16xbf16 batched MFMA GEMM
__global__ __launch_bounds__(256, 2) void gemm_bb(
    const bf16_t* __restrict__ A, long aO, long aI, int lda,
    const bf16_t* __restrict__ B, long bO, long bI, int ldb,
    void* __restrict__ Cv, long cO, long cI, int ldc,
    int K_len, int out_bf16) {
    __shared__ bf16_t As[128 * 32];
    __shared__ bf16_t Bs[128 * 32];
    const int tid = threadIdx.x;
    const int lane = tid & 63;
    const int wave = tid >> 6;
    const int z = blockIdx.z, zb = z >> 2, zh = z & 3;
    const bf16_t* Az = A + (long)zb * aO + (long)zh * aI;
    const bf16_t* Bz = B + (long)zb * bO + (long)zh * bI;
    const int m0 = blockIdx.y * 128;
    const int n0 = blockIdx.x * 128;

    const int cA = wave * 2;
    const bf16_t* gA0 = Az + (long)(m0 + cA * 16 + (lane >> 2)) * lda + (lane & 3) * 8;
    const bf16_t* gA1 = gA0 + 16L * lda;
    const bf16_t* gB0 = Bz + (long)(n0 + cA * 16 + (lane >> 2)) * ldb + (lane & 3) * 8;
    const bf16_t* gB1 = gB0 + 16L * ldb;
    bf16_t* lA0 = &As[cA * 512];
    bf16_t* lA1 = lA0 + 512;
    bf16_t* lB0 = &Bs[cA * 512];
    bf16_t* lB1 = lB0 + 512;

    const int wr = wave >> 1, wc = wave & 1;
    const int fr = lane & 15, fq = lane >> 4;
    const bf16_t* aBase = &As[(wr * 64 + fr) * 32 + fq * 8];
    const bf16_t* bBase = &Bs[(wc * 64 + fr) * 32 + fq * 8];

    f32x4 acc[4][4] = {};

    for (int kk = 0; kk < K_len; kk += 32) {
        gload_lds16(gA0, lA0);
        gload_lds16(gA1, lA1);
        gload_lds16(gB0, lB0);
        gload_lds16(gB1, lB1);
        gA0 += 32; gA1 += 32; gB0 += 32; gB1 += 32;
        __syncthreads();
        bf16x8 af[4], bfr[4];
#pragma unroll
        for (int m = 0; m < 4; ++m) af[m] = *(const bf16x8*)(aBase + m * 512);
#pragma unroll
        for (int n = 0; n < 4; ++n) bfr[n] = *(const bf16x8*)(bBase + n * 512);
#pragma unroll
        for (int m = 0; m < 4; ++m)
#pragma unroll
            for (int n = 0; n < 4; ++n)
                acc[m][n] = __builtin_amdgcn_mfma_f32_16x16x32_bf16(af[m], bfr[n], acc[m][n], 0, 0, 0);
        __syncthreads();
    }

#pragma unroll
    for (int m = 0; m < 4; ++m) {
        const int grow0 = m0 + wr * 64 + m * 16 + fq * 4;
#pragma unroll
        for (int n = 0; n < 4; ++n) {
            const int gcol = n0 + wc * 64 + n * 16 + fr;
#pragma unroll
            for (int r = 0; r < 4; ++r) {
                long idx = (long)(grow0 + r) * ldc + gcol;
                if (out_bf16) {
                    bf16_t* Cb = (bf16_t*)Cv + (long)zb * cO + (long)zh * cI;
                    Cb[idx] = (bf16_t)acc[m][n][r];
                } else {
                    float* Cf = (float*)Cv + (long)zb * cO + (long)zh * cI;
                    Cf[idx] = acc[m][n][r];
                }
            }
        }
    }
}

// ---------------------------------------------------------------- V transpose (attention)
__global__ void vtrans_kernel(const bf16_t* __restrict__ qkvb, bf16_t* __restrict__ vt) {
    int z = blockIdx.z;  // b*4+h
    int b = z >> 2, h = z & 3;
    int d0 = blockIdx.x * 64, k0 = blockIdx.y * 64;
    __shared__ bf16_t tile[64][72];
    int t = threadIdx.x;  // 256
    int r = t >> 2;
    int c4 = (t & 3) * 16;
    const bf16_t* src = qkvb + ((long)(b * SEQL + k0 + r)) * (3 * D_MODEL) + 2 * D_MODEL +
                        h * HEAD_DIM + d0 + c4;
    bf16x8 v0 = *(const bf16x8*)src;
    bf16x8 v1 = *(const bf16x8*)(src + 8);
#pragma unroll
    for (int j = 0; j < 8; ++j) tile[r][c4 + j] = v0[j];
#pragma unroll
    for (int j = 0; j < 8; ++j) tile[r][c4 + 8 + j] = v1[j];
    __syncthreads();
    int dd = t >> 2, kc = (t & 3) * 16;
    bf16_t* dst = vt + (long)z * (HEAD_DIM * SEQL) + (long)(d0 + dd) * SEQL + k0 + kc;
    bf16x8 o0, o1;
#pragma unroll
    for (int j = 0; j < 8; ++j) o0[j] = tile[kc + j][dd];
#pragma unroll
    for (int j = 0; j < 8; ++j) o1[j] = tile[kc + 8 + j][dd];
    *(bf16x8*)dst = o0;
    *(bf16x8*)(dst + 8) = o1;
}

// ---------------------------------------------------------------- softmax rows of S
__global__ void softmax_kernel(const float* __restrict__ S, bf16_t* __restrict__ P) {
    long row = blockIdx.x;  // 4096 = (b,h,q)
    int tid = threadIdx.x;  // 256
    float s = S[row * SEQL + tid] * 0.044194173824159216f;  // 1/sqrt(512)
    __shared__ float red[4];
    float m = warp_reduce_max(s);
    if ((tid & 63) == 0) red[tid >> 6] = m;
    __syncthreads();
    float gm = fmaxf(fmaxf(red[0], red[1]), fmaxf(red[2], red[3]));
    __syncthreads();
    float p = __expf(s - gm);
    float su = warp_reduce_sum(p);
    if ((tid & 63) == 0) red[tid >> 6] = su;
    __syncthreads();
    float gs = red[0] + red[1] + red[2] + red[3];
    P[row * SEQL + tid] = (bf16_t)(p / gs);
}

// ---------------------------------------------------------------- conv + silu + transpose
__global__ void conv_tr_kernel(const bf16_t* __restrict__ xzb, const float* __restrict__ cw,
                               const float* __restrict__ cb, bf16_t* __restrict__ xT,
                               bf16_t* __restrict__ xcb, bf16_t* __restrict__ zT) {
    __shared__ bf16_t xin[68][64];
    __shared__ bf16_t outt[64][72];  // [e_local][l_local]
    const int e0 = blockIdx.x * 64, l0 = blockIdx.y * 64, b = blockIdx.z;
    const int t = threadIdx.x;
    const int r = t >> 4;            // 0..15
    const int c = (t & 15) * 4;      // 0..60

#pragma unroll
    for (int i = 0; i < 5; ++i) {
        int m = r + i * 16;
        if (m < 67) {
            int l = l0 - 3 + m;
            bf16x4 v;
            if (l >= 0)
                v = *(const bf16x4*)(xzb + ((long)(b * SEQL + l)) * (2 * ED) + e0 + c);
            else {
                v[0] = (bf16_t)0.f; v[1] = (bf16_t)0.f; v[2] = (bf16_t)0.f; v[3] = (bf16_t)0.f;
            }
            *(bf16x4*)&xin[m][c] = v;
        }
    }
    __syncthreads();

    {
        const int e_l = t & 63;
        const int lbase = (t >> 6) * 16;
        const float4 wv = *(const float4*)(cw + (long)(e0 + e_l) * 4);
        const float bias = cb[e0 + e_l];
#pragma unroll
        for (int k = 0; k < 16; ++k) {
            int l = lbase + k;
            float acc = bias + wv.x * (float)xin[l][e_l] + wv.y * (float)xin[l + 1][e_l] +
                        wv.z * (float)xin[l + 2][e_l] + wv.w * (float)xin[l + 3][e_l];
            float s = acc / (1.f + __expf(-acc));
            outt[e_l][l] = (bf16_t)s;
        }
    }
    __syncthreads();

    {
        int er = t >> 2, lc = (t & 3) * 16;
        bf16x8 a = *(bf16x8*)&outt[er][lc];
        bf16x8 bb8 = *(bf16x8*)&outt[er][lc + 8];
        bf16_t* dst = xT + ((long)b * ED + e0 + er) * SEQL + l0 + lc;
        *(bf16x8*)dst = a;
        *(bf16x8*)(dst + 8) = bb8;
    }
    {
        int lr = t >> 2, ec = (t & 3) * 16;
        bf16_t tmp[16];
#pragma unroll
        for (int j = 0; j < 16; ++j) tmp[j] = outt[ec + j][lr];
        bf16_t* dst = xcb + ((long)(b * SEQL + l0 + lr)) * ED + e0 + ec;
        *(bf16x8*)dst = *(bf16x8*)&tmp[0];
        *(bf16x8*)(dst + 8) = *(bf16x8*)&tmp[8];
    }
    __syncthreads();

#pragma unroll
    for (int i = 0; i < 4; ++i) {
        int m = r + i * 16;
        bf16x4 v = *(const bf16x4*)(xzb + ((long)(b * SEQL + l0 + m)) * (2 * ED) + ED + e0 + c);
        *(bf16x4*)&xin[m][c] = v;
    }
    __syncthreads();
    {
        int er = t >> 2, lc = (t & 3) * 16;
        bf16_t tz[16];
#pragma unroll
        for (int j = 0; j < 16; ++j) tz[j] = xin[lc + j][er];
        bf16_t* dst = zT + ((long)b * ED + e0 + er) * SEQL + l0 + lc;
        *(bf16x8*)dst = *(bf16x8*)&tz[0];
        *(bf16x8*)(dst + 8) = *(bf16x8*)&tz[8];
    }
}

// ---------------------------------------------------------------- softplus + transpose
__global__ void softplus_tr_kernel(const float* __restrict__ delta, const float* __restrict__ dt_b,
                                   float* __restrict__ dT) {
    __shared__ float tile[64][65];
    const int e0 = blockIdx.x * 64, l0 = blockIdx.y * 64, b = blockIdx.z;
    const int t = threadIdx.x;
    const int r = t >> 4, c = (t & 15) * 4;
#pragma unroll
    for (int i = 0; i < 4; ++i) {
        int l = r + i * 16;
        float4 v = *(const float4*)(delta + ((long)(b * SEQL + l0 + l)) * ED + e0 + c);
        float4 bb = *(const float4*)(dt_b + e0 + c);
        float u0 = v.x + bb.x, u1 = v.y + bb.y, u2 = v.z + bb.z, u3 = v.w + bb.w;
        tile[l][c] = (u0 > 20.f) ? u0 : log1pf(__expf(u0));
        tile[l][c + 1] = (u1 > 20.f) ? u1 : log1pf(__expf(u1));
        tile[l][c + 2] = (u2 > 20.f) ? u2 : log1pf(__expf(u2));
        tile[l][c + 3] = (u3 > 20.f) ? u3 : log1pf(__expf(u3));
    }
    __syncthreads();
#pragma unroll
    for (int i = 0; i < 4; ++i) {
        int ee = r + i * 16;
        float4 w;
        w.x = tile[c][ee];
        w.y = tile[c + 1][ee];
        w.z = tile[c + 2][ee];
        w.w = tile[c + 3][ee];
        *(float4*)(dT + ((long)b * ED + e0 + ee) * SEQL + l0 + c) = w;
    }
}

// ---------------------------------------------------------------- chunk-parallel selective scan
__global__ __launch_bounds__(256) void scan_chunk_kernel(
    const float* __restrict__ dT, const bf16_t* __restrict__ xT, const bf16_t* __restrict__ zT,
    const float* __restrict__ dbc, const float* __restrict__ A_log, const float* __restrict__ Dp,
    bf16_t* __restrict__ yT) {
    const int t = threadIdx.x;
    const int chunk = t & 15;
    const int el = t >> 4;
    const int b = blockIdx.y;
    const int e = blockIdx.x * 16 + el;
    const int l0 = chunk * 16;

    float Ar[16];
    {
        const float* ap = A_log + (long)e * D_STATE;
#pragma unroll
        for (int n = 0; n < 16; n += 4) {
            float4 v = *(const float4*)(ap + n);
            Ar[n] = -__expf(v.x);
            Ar[n + 1] = -__expf(v.y);
            Ar[n + 2] = -__expf(v.z);
            Ar[n + 3] = -__expf(v.w);
        }
    }
    float d[16];
    {
        const float* dp = dT + ((long)b * ED + e) * SEQL + l0;
#pragma unroll
        for (int j = 0; j < 16; j += 4) *(float4*)&d[j] = *(const float4*)(dp + j);
    }
    float xf[16];
    {
        const bf16_t* xp = xT + ((long)b * ED + e) * SEQL + l0;
        bf16x8 x0 = *(const bf16x8*)xp;
        bf16x8 x1 = *(const bf16x8*)(xp + 8);
#pragma unroll
        for (int j = 0; j < 8; ++j) {
            xf[j] = (float)x0[j];
            xf[8 + j] = (float)x1[j];
        }
    }
    const float* bcbase = dbc + ((long)b * SEQL) * (DT_RANK + 2 * D_STATE) + DT_RANK;

    float P[16], S[16];
#pragma unroll
    for (int n = 0; n < 16; ++n) {
        P[n] = 1.f;
        S[n] = 0.f;
    }

#pragma unroll
    for (int j = 0; j < 16; ++j) {
        const float* br = bcbase + (long)(l0 + j) * (DT_RANK + 2 * D_STATE);
        float Bv[16];
#pragma unroll
        for (int n = 0; n < 16; n += 4) *(float4*)&Bv[n] = *(const float4*)(br + n);
        float dx = d[j] * xf[j];
#pragma unroll
        for (int n = 0; n < 16; ++n) {
            float dA = __expf(d[j] * Ar[n]);
            S[n] = dA * S[n] + dx * Bv[n];
            P[n] *= dA;
        }
    }

#pragma unroll
    for (int off = 1; off < 16; off <<= 1) {
        float Pp[16], Sp[16];
#pragma unroll
        for (int n = 0; n < 16; ++n) {
            Pp[n] = __shfl_up(P[n], off, 16);
            Sp[n] = __shfl_up(S[n], off, 16);
        }
        if (chunk >= off) {
#pragma unroll
            for (int n = 0; n < 16; ++n) {
                S[n] = P[n] * Sp[n] + S[n];
                P[n] *= Pp[n];
            }
        }
    }

    float h[16];
#pragma unroll
    for (int n = 0; n < 16; ++n) {
        float hs = __shfl_up(S[n], 1, 16);
        h[n] = (chunk == 0) ? 0.f : hs;
    }

    const float dpe = Dp[e];
    float zf[16];
    {
        const bf16_t* zp = zT + ((long)b * ED + e) * SEQL + l0;
        bf16x8 z0 = *(const bf16x8*)zp;
        bf16x8 z1 = *(const bf16x8*)(zp + 8);
#pragma unroll
        for (int j = 0; j < 8; ++j) {
            zf[j] = (float)z0[j];
            zf[8 + j] = (float)z1[j];
        }
    }

    bf16_t yv[16];
#pragma unroll
    for (int j = 0; j < 16; ++j) {
        const float* br = bcbase + (long)(l0 + j) * (DT_RANK + 2 * D_STATE);
        float Bv[16], Cv[16];
#pragma unroll
        for (int n = 0; n < 16; n += 4) *(float4*)&Bv[n] = *(const float4*)(br + n);
#pragma unroll
        for (int n = 0; n < 16; n += 4) *(float4*)&Cv[n] = *(const float4*)(br + D_STATE + n);
        float dx = d[j] * xf[j];
        float y = 0.f;
#pragma unroll
        for (int n = 0; n < 16; ++n) {
            float dA = __expf(d[j] * Ar[n]);
            h[n] = dA * h[n] + dx * Bv[n];
            y += h[n] * Cv[n];
        }
        y += xf[j] * dpe;
        float z = zf[j];
        y *= z / (1.f + __expf(-z));
        yv[j] = (bf16_t)y;
    }
    bf16_t* yp = yT + ((long)b * ED + e) * SEQL + l0;
    *(bf16x8*)yp = *(bf16x8*)&yv[0];
    *(bf16x8*)(yp + 8) = *(bf16x8*)&yv[8];
}

// ---------------------------------------------------------------- yT [B][ED][L] -> Y [B*L][ED]
__global__ void ytr_kernel(const bf16_t* __restrict__ yT, bf16_t* __restrict__ Y) {
    __shared__ bf16_t tl[64][72];
    const int e0 = blockIdx.x * 64, l0 = blockIdx.y * 64, b = blockIdx.z;
    const int t = threadIdx.x;
    {
        int er = t >> 2, lc = (t & 3) * 16;
        const bf16_t* src = yT + ((long)b * ED + e0 + er) * SEQL + l0 + lc;
        bf16x8 a = *(const bf16x8*)src;
        bf16x8 bb8 = *(const bf16x8*)(src + 8);
        *(bf16x8*)&tl[er][lc] = a;
        *(bf16x8*)&tl[er][lc + 8] = bb8;
    }
    __syncthreads();
    {
        int lr = t >> 2, ec = (t & 3) * 16;
        bf16_t tmp[16];
#pragma unroll
        for (int j = 0; j < 16; ++j) tmp[j] = tl[ec + j][lr];
        bf16_t* dst = Y + ((long)(b * SEQL + l0 + lr)) * ED + e0 + ec;
        *(bf16x8*)dst = *(bf16x8*)&tmp[0];
        *(bf16x8*)(dst + 8) = *(bf16x8*)&tmp[8];
    }
}

// ---------------------------------------------------------------- head GEMV1
__global__ void head_gemv1(const float* __restrict__ H, const float* __restrict__ w1,
                           const float* __restrict__ b1, float* __restrict__ hm1) {
    int b = blockIdx.y;
    int wave = threadIdx.x >> 6, lane = threadIdx.x & 63;
    int n = blockIdx.x * 4 + wave;
    const float* last = H + ((long)(b * SEQL + SEQL - 1)) * D_MODEL;
    const float* wr = w1 + (long)n * D_MODEL;
    float s = 0.f;
    for (int j = lane * 4; j < D_MODEL; j += 256) {
        float4 a = *(const float4*)(last + j);
        float4 w = *(const float4*)(wr + j);
        s += a.x * w.x + a.y * w.y + a.z * w.z + a.w * w.w;
    }
    s = warp_reduce_sum(s);
    if (lane == 0) hm1[b * 1024 + n] = s + b1[n];
}

// ---------------------------------------------------------------- head final
__global__ void head_final(const float* __restrict__ hm1, const float* __restrict__ ln_g,
                           const float* __restrict__ ln_b, const float* __restrict__ w2,
                           const float* __restrict__ b2, float* __restrict__ out) {
    int b = blockIdx.x;
    int tid = threadIdx.x;  // 1024
    __shared__ float hm[1024];
    __shared__ float r1[16], r2[16];
    __shared__ float stats[2];
    __shared__ float outs[64];

    float v = hm1[b * 1024 + tid];
    float s1 = warp_reduce_sum(v);
    float s2 = warp_reduce_sum(v * v);
    int wave = tid >> 6;
    if ((tid & 63) == 0) { r1[wave] = s1; r2[wave] = s2; }
    __syncthreads();
    if (tid == 0) {
        float t1 = 0.f, t2 = 0.f;
        for (int w = 0; w < 16; ++w) { t1 += r1[w]; t2 += r2[w]; }
        float mean = t1 / 1024.f;
        stats[0] = mean;
        stats[1] = rsqrtf(t2 / 1024.f - mean * mean + 1e-5f);
    }
    __syncthreads();
    float x = (v - stats[0]) * stats[1] * ln_g[tid] + ln_b[tid];
    x = (x > 0.f) ? x : (__expf(x) - 1.f);
    hm[tid] = x;
    __syncthreads();

    int o = tid >> 4, kk = tid & 15;
    float a = 0.f;
    const float* w2r = w2 + (long)o * 1024;
    for (int j = kk; j < 1024; j += 16) a += hm[j] * w2r[j];
#pragma unroll
    for (int off = 1; off < 16; off <<= 1) a += __shfl_xor(a, off);
    if (kk == 0) outs[o] = a + b2[o];
    __syncthreads();
    if (tid < 64) {
        float vv = outs[tid];
        float ss = warp_reduce_sum(vv * vv);
        out[b * 64 + tid] = vv / fmaxf(sqrtf(ss), 1e-12f);
    }
}

// ---------------------------------------------------------------- launch
extern "C" void kernel_launch(void* const* d_in, const int* in_sizes, int n_in,
                              void* d_out, int out_size, void* d_ws, size_t ws_size,
                              hipStream_t stream) {
    const float* x = (const float*)d_in[0];
    const float* norm_w = (const float*)d_in[1];
    const float* in_proj_w = (const float*)d_in[2];
    const float* conv_w = (const float*)d_in[3];
    const float* conv_b = (const float*)d_in[4];
    const float* x_proj_w = (const float*)d_in[5];
    const float* dt_proj_w = (const float*)d_in[6];
    const float* dt_proj_b = (const float*)d_in[7];
    const float* A_log = (const float*)d_in[8];
    const float* D_param = (const float*)d_in[9];
    const float* out_proj_w = (const float*)d_in[10];
    const float* attn_in_w = (const float*)d_in[11];
    const float* attn_in_b = (const float*)d_in[12];
    const float* attn_out_w = (const float*)d_in[13];
    const float* attn_out_b = (const float*)d_in[14];
    const float* w1 = (const float*)d_in[15];
    const float* b1 = (const float*)d_in[16];
    const float* ln_g = (const float*)d_in[17];
    const float* ln_b = (const float*)d_in[18];
    const float* w2 = (const float*)d_in[19];
    const float* b2 = (const float*)d_in[20];

    float* ws = (float*)d_ws;
    size_t o = 0;
    float* H = ws + o;      o += 2097152;       // (B,L,D) fp32
    float* SCR = ws + o;    o += 6291456;       // XZb/dT/yT (mamba) | QKV etc (attn) | splitK partials
    float* DELTA = ws + o;  o += 4194304;       // (B,L,ED) fp32  (contiguous after SCR)
    float* DBC = ws + o;    o += 163840;        // (B,L,160) fp32
    float* XPART = ws + o;  o += 1310720;       // 8 x (1024,160) split-K partials
    bf16_t* XNb = (bf16_t*)(ws + o);  o += 1048576;  // (B,L,D) bf16
    bf16_t* XCb = (bf16_t*)(ws + o);  o += 2097152;  // (B,L,ED) bf16
    bf16_t* DTb = (bf16_t*)(ws + o);  o += 65536;    // (1024,128) bf16
    bf16_t* Yb = (bf16_t*)(ws + o);   o += 2097152;  // (B,L,ED) bf16
    bf16_t* Hb = (bf16_t*)(ws + o);   o += 1048576;  // (B,L,D) bf16
    bf16_t* AOb = (bf16_t*)(ws + o);  o += 1048576;  // (B,L,D) bf16
    float* HM1 = ws + o;    o += 4096;          // (B,1024) fp32
    bf16_t* XT = (bf16_t*)(ws + o);   o += 2097152;  // [B][ED][L] bf16
    bf16_t* ZT = (bf16_t*)(ws + o);   o += 2097152;  // [B][ED][L] bf16

    bf16_t* XZb = (bf16_t*)SCR;                       // [B*L][2ED] bf16 (dead after conv_tr)
    float* DTT = SCR;                                 // [B][ED][L] f32 (aliases XZb; written after)
    bf16_t* YTT = (bf16_t*)(SCR + 4194304);           // [B][ED][L] bf16
    float* PART = SCR;                                // splitK partials (SCR+DELTA contiguous, 10.4M floats)

    bf16_t* QKVb = (bf16_t*)SCR;                      // attention phase
    float* SBUF = SCR + 3145728;
    bf16_t* Pb = (bf16_t*)(SCR + 3145728 + 1048576);
    bf16_t* VTb = (bf16_t*)(SCR + 3145728 + 1048576 + 524288);

    const int M = BATCH * SEQL;  // 1024
    const long S_H = (long)M * D_MODEL;

    copy_kernel<<<(S_H + 255) / 256, 256, 0, stream>>>(x, H, (int)S_H);

    for (int i = 0; i < N_LAYERS; ++i) {
        rmsnorm_kernel<<<M, 256, 0, stream>>>(H, norm_w + (long)i * D_MODEL, XNb);
        gemm_bf16<<<dim3(64, 8, 1), 256, 0, stream>>>(
            XNb, D_MODEL, in_proj_w + (long)i * 2 * ED * D_MODEL, D_MODEL, (float*)XZb, 2 * ED,
            2 * ED, D_MODEL, nullptr, 0, 1, 0);
        conv_tr_kernel<<<dim3(64, 4, 4), 256, 0, stream>>>(
            XZb, conv_w + (long)i * ED * D_CONV, conv_b + (long)i * ED, XT, XCb, ZT);
        gemm_bf16<<<dim3(2, 8, 8), 256, 0, stream>>>(
            XCb, ED, x_proj_w + (long)i * (DT_RANK + 2 * D_STATE) * ED, ED, XPART,
            DT_RANK + 2 * D_STATE, DT_RANK + 2 * D_STATE, ED / 8, nullptr, 0, 0,
            (long)M * (DT_RANK + 2 * D_STATE));
        ksum_kernel<<<640, 256, 0, stream>>>(XPART, DBC, M * (DT_RANK + 2 * D_STATE), 8,
                                             (long)M * (DT_RANK + 2 * D_STATE));
        dt_pack_kernel<<<512, 256, 0, stream>>>(DBC, DTb);
        gemm_bf16<<<dim3(32, 8, 1), 256, 0, stream>>>(
            DTb, DT_RANK, dt_proj_w + (long)i * ED * DT_RANK, DT_RANK, DELTA, ED, ED, DT_RANK,
            nullptr, 0, 0, 0);
        softplus_tr_kernel<<<dim3(64, 4, 4), 256, 0, stream>>>(DELTA, dt_proj_b + (long)i * ED,
                                                               DTT);
        scan_chunk_kernel<<<dim3(ED / 16, BATCH), 256, 0, stream>>>(
            DTT, XT, ZT, DBC, A_log + (long)i * ED * D_STATE, D_param + (long)i * ED, YTT);
        ytr_kernel<<<dim3(64, 4, 4), 256, 0, stream>>>(YTT, Yb);
        // out_proj: split-K=4 (512 blocks) -> fp32 partials over dead SCR/DELTA, then add into H
        gemm_bf16<<<dim3(16, 8, 4), 256, 0, stream>>>(
            Yb, ED, out_proj_w + (long)i * D_MODEL * ED, ED, PART, D_MODEL, D_MODEL, ED / 4,
            nullptr, 0, 0, (long)M * D_MODEL);
        ksum_add_kernel<<<8192, 256, 0, stream>>>(PART, H, M * D_MODEL, 4, (long)M * D_MODEL,
                                                  nullptr, 0);
    }

    f2b_kernel<<<(int)((S_H + 255) / 256), 256, 0, stream>>>(H, Hb, (int)S_H);
    gemm_bf16<<<dim3(48, 8, 1), 256, 0, stream>>>(Hb, D_MODEL, attn_in_w, D_MODEL, (float*)QKVb,
                                                  3 * D_MODEL, 3 * D_MODEL, D_MODEL, attn_in_b, 0,
                                                  1, 0);
    vtrans_kernel<<<dim3(8, 4, 16), 256, 0, stream>>>(QKVb, VTb);
    gemm_bb<<<dim3(2, 2, 16), 256, 0, stream>>>(
        QKVb, (long)SEQL * 3 * D_MODEL, HEAD_DIM, 3 * D_MODEL,
        QKVb + D_MODEL, (long)SEQL * 3 * D_MODEL, HEAD_DIM, 3 * D_MODEL,
        SBUF, 4L * SEQL * SEQL, (long)SEQL * SEQL, SEQL, HEAD_DIM, 0);
    softmax_kernel<<<BATCH * N_HEADS * SEQL, 256, 0, stream>>>(SBUF, Pb);
    gemm_bb<<<dim3(4, 2, 16), 256, 0, stream>>>(
        Pb, 4L * SEQL * SEQL, (long)SEQL * SEQL, SEQL,
        VTb, 4L * HEAD_DIM * SEQL, (long)HEAD_DIM * SEQL, SEQL,
        AOb, (long)SEQL * D_MODEL, HEAD_DIM, D_MODEL, SEQL, 1);
    // attn_out: split-K=4 (512 blocks); bias folded into the reduce (added once)
    gemm_bf16<<<dim3(16, 8, 4), 256, 0, stream>>>(
        AOb, D_MODEL, attn_out_w, D_MODEL, PART, D_MODEL, D_MODEL, D_MODEL / 4, nullptr, 0, 0,
        (long)M * D_MODEL);
    ksum_add_kernel<<<8192, 256, 0, stream>>>(PART, H, M * D_MODEL, 4, (long)M * D_MODEL,
                                              attn_out_b, D_MODEL - 1);

    head_gemv1<<<dim3(256, 4), 256, 0, stream>>>(H, w1, b1, HM1);
    head_final<<<BATCH, 1024, 0, stream>>>(HM1, ln_g, ln_b, w2, b2, (float*)d_out);
}